// Round 1
// baseline (1360.797 us; speedup 1.0000x reference)
//
#include <hip/hip_runtime.h>

#define NN 10000
#define EE 80000
#define DD 32
#define DEDGE 16
#define LL 3
#define D2V 1024
#define RSTRIDE 20  // floats per LDS row: 16 w + bias + ln_g + ln_b + pad; 80B rows -> conflict-free b128

__device__ __forceinline__ float dot16(const float4* w, const float4* a) {
    float acc = 0.f;
#pragma unroll
    for (int c = 0; c < 4; ++c) {
        acc = fmaf(w[c].x, a[c].x, acc);
        acc = fmaf(w[c].y, a[c].y, acc);
        acc = fmaf(w[c].z, a[c].z, acc);
        acc = fmaf(w[c].w, a[c].w, acc);
    }
    return acc;
}

// Per-layer fused: edge-MLP (Linear 16->1024 + LN + ReLU) recomputed on the fly,
// message = x[src] @ We, atomic scatter-add into agg[tgt].
__global__ __launch_bounds__(256) void edge_kernel(
    const float* __restrict__ x,
    const int* __restrict__ edge_index,
    const float* __restrict__ edge_attr,
    const float* __restrict__ emlp_w,
    const float* __restrict__ emlp_b,
    const float* __restrict__ elng,
    const float* __restrict__ elnb,
    float* __restrict__ agg)
{
    __shared__ float wl[D2V * RSTRIDE];  // 80 KB
    for (int r = threadIdx.x; r < D2V; r += 256) {
        const float4* s = (const float4*)(emlp_w + r * DEDGE);
        float4* d = (float4*)(wl + r * RSTRIDE);
        d[0] = s[0]; d[1] = s[1]; d[2] = s[2]; d[3] = s[3];
        wl[r * RSTRIDE + 16] = emlp_b[r];
        wl[r * RSTRIDE + 17] = elng[r];
        wl[r * RSTRIDE + 18] = elnb[r];
    }
    __syncthreads();

    const int lane = threadIdx.x & 63;
    const int f = lane & 31;       // output column of We owned by this lane
    const int half = lane >> 5;    // which half of the d-range
    const int wid = (blockIdx.x * 256 + threadIdx.x) >> 6;
    const int nw = gridDim.x * 4;

    for (int g = wid; g < EE / 4; g += nw) {
        const int e0 = g * 4;
        int si[4], ti[4];
        float4 ea[4][4];
#pragma unroll
        for (int j = 0; j < 4; ++j) {
            si[j] = edge_index[e0 + j];
            ti[j] = edge_index[EE + e0 + j];
            const float4* p = (const float4*)(edge_attr + (e0 + j) * DEDGE);
            ea[j][0] = p[0]; ea[j][1] = p[1]; ea[j][2] = p[2]; ea[j][3] = p[3];
        }
        float h[4][16];
        float s1[4] = {0.f, 0.f, 0.f, 0.f};
        float s2[4] = {0.f, 0.f, 0.f, 0.f};
#pragma unroll
        for (int d16 = 0; d16 < 16; ++d16) {
            const float* wr = wl + ((half * 16 + d16) * 32 + f) * RSTRIDE;
            float4 w[4];
            w[0] = *(const float4*)(wr);
            w[1] = *(const float4*)(wr + 4);
            w[2] = *(const float4*)(wr + 8);
            w[3] = *(const float4*)(wr + 12);
            const float bias = wr[16];
#pragma unroll
            for (int j = 0; j < 4; ++j) {
                float acc = bias + dot16(w, ea[j]);
                h[j][d16] = acc;
                s1[j] += acc;
                s2[j] = fmaf(acc, acc, s2[j]);
            }
        }
        // LN stats over the 1024 entries of each edge's h (spread 16/lane over 64 lanes)
#pragma unroll
        for (int j = 0; j < 4; ++j) {
#pragma unroll
            for (int off = 32; off >= 1; off >>= 1) {
                s1[j] += __shfl_xor(s1[j], off);
                s2[j] += __shfl_xor(s2[j], off);
            }
        }
        float m[4], inv[4];
#pragma unroll
        for (int j = 0; j < 4; ++j) {
            m[j] = s1[j] * (1.f / 1024.f);
            float v = s2[j] * (1.f / 1024.f) - m[j] * m[j];
            inv[j] = rsqrtf(v + 1e-5f);
        }
        float msg[4] = {0.f, 0.f, 0.f, 0.f};
#pragma unroll
        for (int d16 = 0; d16 < 16; ++d16) {
            const float* wr = wl + ((half * 16 + d16) * 32 + f) * RSTRIDE;
            const float gg = wr[17];
            const float bb = wr[18];
            const int d = half * 16 + d16;
#pragma unroll
            for (int j = 0; j < 4; ++j) {
                float val = fmaf((h[j][d16] - m[j]) * inv[j], gg, bb);
                val = fmaxf(val, 0.f);
                msg[j] = fmaf(x[si[j] * 32 + d], val, msg[j]);
            }
        }
#pragma unroll
        for (int j = 0; j < 4; ++j) {
            float mm = msg[j] + __shfl_xor(msg[j], 32);
            if (half == 0) atomicAdd(&agg[ti[j] * 32 + f], mm);
        }
    }
}

// Per-layer node update: out = LN(agg + x@(root+res)^T + (conv_b+res_b))
__global__ __launch_bounds__(256) void node_kernel(
    const float* __restrict__ x,
    const float* __restrict__ agg,
    const float* __restrict__ root_w,
    const float* __restrict__ conv_b,
    const float* __restrict__ res_w,
    const float* __restrict__ res_b,
    const float* __restrict__ lng,
    const float* __restrict__ lnb,
    float* __restrict__ out)
{
    __shared__ float ws[D2V];
    __shared__ float bs[DD], gs[DD], bbs[DD];
    for (int i = threadIdx.x; i < D2V; i += 256) ws[i] = root_w[i] + res_w[i];
    if (threadIdx.x < DD) {
        bs[threadIdx.x] = conv_b[threadIdx.x] + res_b[threadIdx.x];
        gs[threadIdx.x] = lng[threadIdx.x];
        bbs[threadIdx.x] = lnb[threadIdx.x];
    }
    __syncthreads();
    const int n = blockIdx.x * 256 + threadIdx.x;
    if (n >= NN) return;
    float xr[DD], pre[DD];
    {
        const float4* p = (const float4*)(x + n * DD);
        const float4* q = (const float4*)(agg + n * DD);
#pragma unroll
        for (int c = 0; c < 8; ++c) {
            float4 t = p[c];
            xr[4 * c] = t.x; xr[4 * c + 1] = t.y; xr[4 * c + 2] = t.z; xr[4 * c + 3] = t.w;
            float4 u = q[c];
            pre[4 * c] = u.x; pre[4 * c + 1] = u.y; pre[4 * c + 2] = u.z; pre[4 * c + 3] = u.w;
        }
    }
    float s1 = 0.f, s2 = 0.f;
#pragma unroll
    for (int ff = 0; ff < DD; ++ff) {
        float acc = pre[ff] + bs[ff];
        const float* wr = ws + ff * DD;
#pragma unroll
        for (int dd = 0; dd < DD; ++dd) acc = fmaf(xr[dd], wr[dd], acc);
        pre[ff] = acc;
        s1 += acc;
        s2 = fmaf(acc, acc, s2);
    }
    const float m = s1 * (1.f / 32.f);
    const float v = s2 * (1.f / 32.f) - m * m;
    const float inv = rsqrtf(v + 1e-5f);
    float4* op = (float4*)(out + n * DD);
#pragma unroll
    for (int c = 0; c < 8; ++c) {
        float4 t;
        t.x = fmaf((pre[4 * c + 0] - m) * inv, gs[4 * c + 0], bbs[4 * c + 0]);
        t.y = fmaf((pre[4 * c + 1] - m) * inv, gs[4 * c + 1], bbs[4 * c + 1]);
        t.z = fmaf((pre[4 * c + 2] - m) * inv, gs[4 * c + 2], bbs[4 * c + 2]);
        t.w = fmaf((pre[4 * c + 3] - m) * inv, gs[4 * c + 3], bbs[4 * c + 3]);
        op[c] = t;
    }
}

// fused = relu(LN(concat(out0,out1,out2) @ fuse_w.T + fuse_b))
__global__ __launch_bounds__(256) void fuse_kernel(
    const float* __restrict__ o0,
    const float* __restrict__ o1,
    const float* __restrict__ o2,
    const float* __restrict__ fw,
    const float* __restrict__ fb,
    const float* __restrict__ g,
    const float* __restrict__ b,
    float* __restrict__ out)
{
    __shared__ float ws[DD * 96];
    __shared__ float fbs[DD], gs[DD], bbs[DD];
    for (int i = threadIdx.x; i < DD * 96; i += 256) ws[i] = fw[i];
    if (threadIdx.x < DD) {
        fbs[threadIdx.x] = fb[threadIdx.x];
        gs[threadIdx.x] = g[threadIdx.x];
        bbs[threadIdx.x] = b[threadIdx.x];
    }
    __syncthreads();
    const int n = blockIdx.x * 256 + threadIdx.x;
    if (n >= NN) return;
    float cat[96];
    {
        const float4* p0 = (const float4*)(o0 + n * DD);
        const float4* p1 = (const float4*)(o1 + n * DD);
        const float4* p2 = (const float4*)(o2 + n * DD);
#pragma unroll
        for (int c = 0; c < 8; ++c) {
            float4 t0 = p0[c];
            cat[4 * c] = t0.x; cat[4 * c + 1] = t0.y; cat[4 * c + 2] = t0.z; cat[4 * c + 3] = t0.w;
            float4 t1 = p1[c];
            cat[32 + 4 * c] = t1.x; cat[32 + 4 * c + 1] = t1.y; cat[32 + 4 * c + 2] = t1.z; cat[32 + 4 * c + 3] = t1.w;
            float4 t2 = p2[c];
            cat[64 + 4 * c] = t2.x; cat[64 + 4 * c + 1] = t2.y; cat[64 + 4 * c + 2] = t2.z; cat[64 + 4 * c + 3] = t2.w;
        }
    }
    float pre[DD];
    float s1 = 0.f, s2 = 0.f;
#pragma unroll
    for (int ff = 0; ff < DD; ++ff) {
        float acc = fbs[ff];
        const float* wr = ws + ff * 96;
#pragma unroll
        for (int c = 0; c < 96; ++c) acc = fmaf(cat[c], wr[c], acc);
        pre[ff] = acc;
        s1 += acc;
        s2 = fmaf(acc, acc, s2);
    }
    const float m = s1 * (1.f / 32.f);
    const float v = s2 * (1.f / 32.f) - m * m;
    const float inv = rsqrtf(v + 1e-5f);
    float4* op = (float4*)(out + n * DD);
#pragma unroll
    for (int c = 0; c < 8; ++c) {
        float4 t;
        t.x = fmaxf(fmaf((pre[4 * c + 0] - m) * inv, gs[4 * c + 0], bbs[4 * c + 0]), 0.f);
        t.y = fmaxf(fmaf((pre[4 * c + 1] - m) * inv, gs[4 * c + 1], bbs[4 * c + 1]), 0.f);
        t.z = fmaxf(fmaf((pre[4 * c + 2] - m) * inv, gs[4 * c + 2], bbs[4 * c + 2]), 0.f);
        t.w = fmaxf(fmaf((pre[4 * c + 3] - m) * inv, gs[4 * c + 3], bbs[4 * c + 3]), 0.f);
        op[c] = t;
    }
}

extern "C" void kernel_launch(void* const* d_in, const int* in_sizes, int n_in,
                              void* d_out, int out_size, void* d_ws, size_t ws_size,
                              hipStream_t stream) {
    const float* x    = (const float*)d_in[0];
    const int*   ei   = (const int*)d_in[1];
    const float* ea   = (const float*)d_in[2];
    const float* emw  = (const float*)d_in[3];
    const float* emb  = (const float*)d_in[4];
    const float* elg  = (const float*)d_in[5];
    const float* elb  = (const float*)d_in[6];
    const float* rootw = (const float*)d_in[7];
    const float* convb = (const float*)d_in[8];
    const float* resw  = (const float*)d_in[9];
    const float* resb  = (const float*)d_in[10];
    const float* lng   = (const float*)d_in[11];
    const float* lnb   = (const float*)d_in[12];
    const float* fw    = (const float*)d_in[13];
    const float* fb    = (const float*)d_in[14];
    const float* flg   = (const float*)d_in[15];
    const float* flb   = (const float*)d_in[16];

    float* out0 = (float*)d_ws;
    float* out1 = out0 + NN * DD;
    float* out2 = out1 + NN * DD;
    float* agg  = out2 + NN * DD;
    float* outs[3] = {out0, out1, out2};

    const float* xin = x;
    for (int l = 0; l < LL; ++l) {
        hipMemsetAsync(agg, 0, NN * DD * sizeof(float), stream);
        edge_kernel<<<512, 256, 0, stream>>>(xin, ei, ea, emw, emb, elg, elb, agg);
        node_kernel<<<(NN + 255) / 256, 256, 0, stream>>>(
            xin, agg, rootw + l * D2V, convb + l * DD, resw + l * D2V, resb + l * DD,
            lng + l * DD, lnb + l * DD, outs[l]);
        xin = outs[l];
    }
    fuse_kernel<<<(NN + 255) / 256, 256, 0, stream>>>(out0, out1, out2, fw, fb, flg, flb,
                                                      (float*)d_out);
}

// Round 2
// 770.448 us; speedup vs baseline: 1.7662x; 1.7662x over previous
//
#include <hip/hip_runtime.h>

#define NN 10000
#define EE 80000
#define DD 32
#define DEDGE 16
#define LL 3
#define D2V 1024

// ---------------- CSR build (once per call) ----------------

__global__ __launch_bounds__(256) void hist_kernel(const int* __restrict__ ei, int* __restrict__ cnt) {
    const int e = blockIdx.x * 256 + threadIdx.x;
    if (e < EE) atomicAdd(&cnt[ei[EE + e]], 1);
}

__global__ __launch_bounds__(1024) void scan_kernel(int* __restrict__ cur, int* __restrict__ off) {
    __shared__ int s[1024];
    const int t = threadIdx.x;
    const int base = t * 10;
    int loc[10];
    int run = 0;
#pragma unroll
    for (int i = 0; i < 10; ++i) {
        const int idx = base + i;
        const int v = (idx < NN) ? cur[idx] : 0;
        loc[i] = run;
        run += v;
    }
    s[t] = run;
    __syncthreads();
    for (int o = 1; o < 1024; o <<= 1) {
        const int v = (t >= o) ? s[t - o] : 0;
        __syncthreads();
        s[t] += v;
        __syncthreads();
    }
    const int excl = s[t] - run;
#pragma unroll
    for (int i = 0; i < 10; ++i) {
        const int idx = base + i;
        if (idx < NN) {
            off[idx] = excl + loc[i];
            cur[idx] = excl + loc[i];
        }
    }
    if (t == 1023) off[NN] = s[1023];
}

__global__ __launch_bounds__(256) void scatter_kernel(const int* __restrict__ ei,
                                                      int* __restrict__ cur,
                                                      int* __restrict__ perm) {
    const int e = blockIdx.x * 256 + threadIdx.x;
    if (e < EE) {
        const int p = atomicAdd(&cur[ei[EE + e]], 1);
        perm[p] = e;
    }
}

// ---------------- LN-stats precompute (once per call) ----------------
// st[0..255]   M[k][j] = mean_r w[r,k]*w[r,j]
// st[256..271] wm[k]   = mean_r w[r,k]
// st[272..287] q[k]    = mean_r b[r]*w[r,k]
// st[288]=bm, st[289]=mean b^2
__global__ __launch_bounds__(256) void prep_stats(const float* __restrict__ w,
                                                  const float* __restrict__ b,
                                                  float* __restrict__ st) {
    const int t = threadIdx.x;
    const int k = t >> 4, j = t & 15;
    float acc = 0.f;
    for (int r = 0; r < D2V; ++r) acc = fmaf(w[r * DEDGE + k], w[r * DEDGE + j], acc);
    st[t] = acc * (1.f / D2V);
    if (t < DEDGE) {
        float s = 0.f, q = 0.f;
        for (int r = 0; r < D2V; ++r) {
            s += w[r * DEDGE + t];
            q = fmaf(b[r], w[r * DEDGE + t], q);
        }
        st[256 + t] = s * (1.f / D2V);
        st[272 + t] = q * (1.f / D2V);
    } else if (t == 16) {
        float s = 0.f, s2 = 0.f;
        for (int r = 0; r < D2V; ++r) {
            s += b[r];
            s2 = fmaf(b[r], b[r], s2);
        }
        st[288] = s * (1.f / D2V);
        st[289] = s2 * (1.f / D2V);
    }
}

// ---------------- per-layer edge message kernel ----------------
// Edge-per-lane, f-split x4: wave W handles edges [(W>>2)*64, +64), columns [ (W&3)*8, +8 ).
// All w/bias/ln reads are wave-uniform -> scalar loads. No LDS, no shuffles.
// LN stats computed analytically from precomputed quadratic form (st).
template <bool GATHER>
__global__ __launch_bounds__(256) void edge_kernel(
    const float* __restrict__ x, const int* __restrict__ ei,
    const float* __restrict__ eattr,
    const float* __restrict__ w, const float* __restrict__ wb,
    const float* __restrict__ lg, const float* __restrict__ lb,
    const float* __restrict__ st, float* __restrict__ out) {
    const int wv = threadIdx.x >> 6;
    const int lane = threadIdx.x & 63;
    const int W = blockIdx.x * 4 + wv;
    const int e = (W >> 2) * 64 + lane;   // grid sized so e < EE always
    const int f0 = (W & 3) * 8;

    const int si = ei[e];
    const int ti = ei[EE + e];
    float ea[16];
    {
        const float4* ep = (const float4*)(eattr + e * DEDGE);
#pragma unroll
        for (int c = 0; c < 4; ++c) {
            const float4 t = ep[c];
            ea[4 * c] = t.x; ea[4 * c + 1] = t.y; ea[4 * c + 2] = t.z; ea[4 * c + 3] = t.w;
        }
    }
    // analytic LN stats over the 1024 pre-LN values
    float m = st[288];
#pragma unroll
    for (int k = 0; k < 16; ++k) m = fmaf(st[256 + k], ea[k], m);
    float ex2 = st[289];
#pragma unroll
    for (int k = 0; k < 16; ++k) {
        float t = 2.f * st[272 + k];
#pragma unroll
        for (int j = 0; j < 16; ++j) t = fmaf(st[k * 16 + j], ea[j], t);
        ex2 = fmaf(t, ea[k], ex2);
    }
    const float var = fmaxf(ex2 - m * m, 0.f);
    const float inv = rsqrtf(var + 1e-5f);
    const float nm = -m;

    const float* xp = x + si * DD;
    float msg[8] = {0.f, 0.f, 0.f, 0.f, 0.f, 0.f, 0.f, 0.f};
#pragma unroll 1
    for (int d = 0; d < DD; ++d) {
        const float xd = xp[d];
        const int r0 = d * 32 + f0;
        const float* wr = w + r0 * DEDGE;   // uniform
        const float* br = wb + r0;          // uniform
        const float* gr = lg + r0;          // uniform
        const float* b2r = lb + r0;         // uniform
#pragma unroll
        for (int f = 0; f < 8; ++f) {
            float h = br[f];
#pragma unroll
            for (int k = 0; k < 16; ++k) h = fmaf(wr[f * 16 + k], ea[k], h);
            const float t1 = inv * gr[f];
            const float t2 = fmaf(nm, t1, b2r[f]);
            float val = fmaf(h, t1, t2);
            val = fmaxf(val, 0.f);
            msg[f] = fmaf(xd, val, msg[f]);
        }
    }
    if constexpr (GATHER) {
        float4* op = (float4*)(out + e * DD + f0);
        op[0] = make_float4(msg[0], msg[1], msg[2], msg[3]);
        op[1] = make_float4(msg[4], msg[5], msg[6], msg[7]);
    } else {
#pragma unroll
        for (int f = 0; f < 8; ++f) atomicAdd(&out[ti * DD + f0 + f], msg[f]);
    }
}

// ---------------- per-layer node update ----------------
// out = LN( gather(msg) + x@(root+res)^T + (conv_b+res_b) )
template <bool GATHER>
__global__ __launch_bounds__(256) void node_kernel(
    const float* __restrict__ x, const float* __restrict__ msg,
    const int* __restrict__ off, const int* __restrict__ perm,
    const float* __restrict__ root_w, const float* __restrict__ conv_b,
    const float* __restrict__ res_w, const float* __restrict__ res_b,
    const float* __restrict__ lng, const float* __restrict__ lnb,
    float* __restrict__ out) {
    __shared__ float wsm[D2V];
    __shared__ float bs[DD], gs[DD], bbs[DD];
    for (int i = threadIdx.x; i < D2V; i += 256) wsm[i] = root_w[i] + res_w[i];
    if (threadIdx.x < DD) {
        bs[threadIdx.x] = conv_b[threadIdx.x] + res_b[threadIdx.x];
        gs[threadIdx.x] = lng[threadIdx.x];
        bbs[threadIdx.x] = lnb[threadIdx.x];
    }
    __syncthreads();
    const int n = blockIdx.x * 256 + threadIdx.x;
    if (n >= NN) return;
    float xr[DD], pre[DD];
    {
        const float4* p = (const float4*)(x + n * DD);
#pragma unroll
        for (int c = 0; c < 8; ++c) {
            const float4 t = p[c];
            xr[4 * c] = t.x; xr[4 * c + 1] = t.y; xr[4 * c + 2] = t.z; xr[4 * c + 3] = t.w;
        }
    }
    if constexpr (GATHER) {
#pragma unroll
        for (int i = 0; i < DD; ++i) pre[i] = 0.f;
        const int k1 = off[n + 1];
        for (int k = off[n]; k < k1; ++k) {
            const float4* mp = (const float4*)(msg + perm[k] * DD);
#pragma unroll
            for (int c = 0; c < 8; ++c) {
                const float4 t = mp[c];
                pre[4 * c] += t.x; pre[4 * c + 1] += t.y;
                pre[4 * c + 2] += t.z; pre[4 * c + 3] += t.w;
            }
        }
    } else {
        const float4* q = (const float4*)(msg + n * DD);
#pragma unroll
        for (int c = 0; c < 8; ++c) {
            const float4 u = q[c];
            pre[4 * c] = u.x; pre[4 * c + 1] = u.y; pre[4 * c + 2] = u.z; pre[4 * c + 3] = u.w;
        }
    }
    float s1 = 0.f, s2 = 0.f;
#pragma unroll
    for (int ff = 0; ff < DD; ++ff) {
        float acc = pre[ff] + bs[ff];
        const float* wr = wsm + ff * DD;
#pragma unroll
        for (int dd = 0; dd < DD; ++dd) acc = fmaf(xr[dd], wr[dd], acc);
        pre[ff] = acc;
        s1 += acc;
        s2 = fmaf(acc, acc, s2);
    }
    const float m = s1 * (1.f / 32.f);
    const float v = s2 * (1.f / 32.f) - m * m;
    const float inv = rsqrtf(v + 1e-5f);
    float4* op = (float4*)(out + n * DD);
#pragma unroll
    for (int c = 0; c < 8; ++c) {
        float4 t;
        t.x = fmaf((pre[4 * c + 0] - m) * inv, gs[4 * c + 0], bbs[4 * c + 0]);
        t.y = fmaf((pre[4 * c + 1] - m) * inv, gs[4 * c + 1], bbs[4 * c + 1]);
        t.z = fmaf((pre[4 * c + 2] - m) * inv, gs[4 * c + 2], bbs[4 * c + 2]);
        t.w = fmaf((pre[4 * c + 3] - m) * inv, gs[4 * c + 3], bbs[4 * c + 3]);
        op[c] = t;
    }
}

// ---------------- fusion head ----------------
__global__ __launch_bounds__(256) void fuse_kernel(
    const float* __restrict__ o0, const float* __restrict__ o1, const float* __restrict__ o2,
    const float* __restrict__ fw, const float* __restrict__ fb,
    const float* __restrict__ g, const float* __restrict__ b,
    float* __restrict__ out) {
    __shared__ float ws[DD * 96];
    __shared__ float fbs[DD], gs[DD], bbs[DD];
    for (int i = threadIdx.x; i < DD * 96; i += 256) ws[i] = fw[i];
    if (threadIdx.x < DD) {
        fbs[threadIdx.x] = fb[threadIdx.x];
        gs[threadIdx.x] = g[threadIdx.x];
        bbs[threadIdx.x] = b[threadIdx.x];
    }
    __syncthreads();
    const int n = blockIdx.x * 256 + threadIdx.x;
    if (n >= NN) return;
    float cat[96];
    {
        const float4* p0 = (const float4*)(o0 + n * DD);
        const float4* p1 = (const float4*)(o1 + n * DD);
        const float4* p2 = (const float4*)(o2 + n * DD);
#pragma unroll
        for (int c = 0; c < 8; ++c) {
            const float4 t0 = p0[c];
            cat[4 * c] = t0.x; cat[4 * c + 1] = t0.y; cat[4 * c + 2] = t0.z; cat[4 * c + 3] = t0.w;
            const float4 t1 = p1[c];
            cat[32 + 4 * c] = t1.x; cat[32 + 4 * c + 1] = t1.y; cat[32 + 4 * c + 2] = t1.z; cat[32 + 4 * c + 3] = t1.w;
            const float4 t2 = p2[c];
            cat[64 + 4 * c] = t2.x; cat[64 + 4 * c + 1] = t2.y; cat[64 + 4 * c + 2] = t2.z; cat[64 + 4 * c + 3] = t2.w;
        }
    }
    float pre[DD];
    float s1 = 0.f, s2 = 0.f;
#pragma unroll
    for (int ff = 0; ff < DD; ++ff) {
        float acc = fbs[ff];
        const float* wr = ws + ff * 96;
#pragma unroll
        for (int c = 0; c < 96; ++c) acc = fmaf(cat[c], wr[c], acc);
        pre[ff] = acc;
        s1 += acc;
        s2 = fmaf(acc, acc, s2);
    }
    const float m = s1 * (1.f / 32.f);
    const float v = s2 * (1.f / 32.f) - m * m;
    const float inv = rsqrtf(v + 1e-5f);
    float4* op = (float4*)(out + n * DD);
#pragma unroll
    for (int c = 0; c < 8; ++c) {
        float4 t;
        t.x = fmaxf(fmaf((pre[4 * c + 0] - m) * inv, gs[4 * c + 0], bbs[4 * c + 0]), 0.f);
        t.y = fmaxf(fmaf((pre[4 * c + 1] - m) * inv, gs[4 * c + 1], bbs[4 * c + 1]), 0.f);
        t.z = fmaxf(fmaf((pre[4 * c + 2] - m) * inv, gs[4 * c + 2], bbs[4 * c + 2]), 0.f);
        t.w = fmaxf(fmaf((pre[4 * c + 3] - m) * inv, gs[4 * c + 3], bbs[4 * c + 3]), 0.f);
        op[c] = t;
    }
}

extern "C" void kernel_launch(void* const* d_in, const int* in_sizes, int n_in,
                              void* d_out, int out_size, void* d_ws, size_t ws_size,
                              hipStream_t stream) {
    const float* x   = (const float*)d_in[0];
    const int*   ei  = (const int*)d_in[1];
    const float* ea  = (const float*)d_in[2];
    const float* emw = (const float*)d_in[3];
    const float* emb = (const float*)d_in[4];
    const float* elg = (const float*)d_in[5];
    const float* elb = (const float*)d_in[6];
    const float* rootw = (const float*)d_in[7];
    const float* convb = (const float*)d_in[8];
    const float* resw  = (const float*)d_in[9];
    const float* resb  = (const float*)d_in[10];
    const float* lng   = (const float*)d_in[11];
    const float* lnb   = (const float*)d_in[12];
    const float* fw    = (const float*)d_in[13];
    const float* fb    = (const float*)d_in[14];
    const float* flg   = (const float*)d_in[15];
    const float* flb   = (const float*)d_in[16];
    float* wsf = (float*)d_ws;

    // GATHER layout (floats): msg[2,560,000] | out0/1/2[3x320,000] | st[320] | ints
    const size_t GATHER_NEED = (size_t)(3520320) * 4 + (size_t)(2 * (NN + 1) + EE) * 4 + 64;
    const bool gather = ws_size >= GATHER_NEED;

    if (gather) {
        float* msg  = wsf;
        float* out0 = wsf + 2560000;
        float* out1 = out0 + NN * DD;
        float* out2 = out1 + NN * DD;
        float* st   = wsf + 3520000;
        int* off  = (int*)(wsf + 3520320);
        int* cur  = off + (NN + 1);
        int* perm = cur + (NN + 1);
        float* outs[3] = {out0, out1, out2};

        hipMemsetAsync(cur, 0, (NN + 1) * sizeof(int), stream);
        hist_kernel<<<313, 256, 0, stream>>>(ei, cur);
        scan_kernel<<<1, 1024, 0, stream>>>(cur, off);
        scatter_kernel<<<313, 256, 0, stream>>>(ei, cur, perm);
        prep_stats<<<1, 256, 0, stream>>>(emw, emb, st);

        const float* xin = x;
        for (int l = 0; l < LL; ++l) {
            edge_kernel<true><<<1250, 256, 0, stream>>>(xin, ei, ea, emw, emb, elg, elb, st, msg);
            node_kernel<true><<<40, 256, 0, stream>>>(xin, msg, off, perm,
                rootw + l * D2V, convb + l * DD, resw + l * D2V, resb + l * DD,
                lng + l * DD, lnb + l * DD, outs[l]);
            xin = outs[l];
        }
        fuse_kernel<<<40, 256, 0, stream>>>(out0, out1, out2, fw, fb, flg, flb, (float*)d_out);
    } else {
        // fallback: atomic scatter into agg (small-ws layout, 5.1 MB)
        float* agg  = wsf;
        float* out0 = wsf + NN * DD;
        float* out1 = out0 + NN * DD;
        float* out2 = out1 + NN * DD;
        float* st   = wsf + 4 * NN * DD;
        float* outs[3] = {out0, out1, out2};

        prep_stats<<<1, 256, 0, stream>>>(emw, emb, st);
        const float* xin = x;
        for (int l = 0; l < LL; ++l) {
            hipMemsetAsync(agg, 0, NN * DD * sizeof(float), stream);
            edge_kernel<false><<<1250, 256, 0, stream>>>(xin, ei, ea, emw, emb, elg, elb, st, agg);
            node_kernel<false><<<40, 256, 0, stream>>>(xin, agg, nullptr, nullptr,
                rootw + l * D2V, convb + l * DD, resw + l * D2V, resb + l * DD,
                lng + l * DD, lnb + l * DD, outs[l]);
            xin = outs[l];
        }
        fuse_kernel<<<40, 256, 0, stream>>>(out0, out1, out2, fw, fb, flg, flb, (float*)d_out);
    }
}

// Round 3
// 266.462 us; speedup vs baseline: 5.1069x; 2.8914x over previous
//
#include <hip/hip_runtime.h>

#define NN 10000
#define EE 80000
#define DD 32
#define DEDGE 16
#define LL 3
#define D2V 1024
#define NTILE 2500  // EE/32

typedef __attribute__((ext_vector_type(8))) short short8v;
typedef __attribute__((ext_vector_type(16))) float f32x16;

__device__ __forceinline__ unsigned short bf16rne(float x) {
    unsigned u = __float_as_uint(x);
    return (unsigned short)((u + 0x7FFF + ((u >> 16) & 1)) >> 16);
}
__device__ __forceinline__ float bf16tof(unsigned short h) {
    return __uint_as_float(((unsigned)h) << 16);
}
__device__ __forceinline__ uint4 pack8(const unsigned short* u) {
    uint4 r;
    r.x = (unsigned)u[0] | ((unsigned)u[1] << 16);
    r.y = (unsigned)u[2] | ((unsigned)u[3] << 16);
    r.z = (unsigned)u[4] | ((unsigned)u[5] << 16);
    r.w = (unsigned)u[6] | ((unsigned)u[7] << 16);
    return r;
}

// ---------------- CSR build (once per call) ----------------
__global__ __launch_bounds__(256) void hist_kernel(const int* __restrict__ ei, int* __restrict__ cnt) {
    const int e = blockIdx.x * 256 + threadIdx.x;
    if (e < EE) atomicAdd(&cnt[ei[EE + e]], 1);
}

__global__ __launch_bounds__(1024) void scan_kernel(int* __restrict__ cur, int* __restrict__ off) {
    __shared__ int s[1024];
    const int t = threadIdx.x;
    const int base = t * 10;
    int loc[10];
    int run = 0;
#pragma unroll
    for (int i = 0; i < 10; ++i) {
        const int idx = base + i;
        const int v = (idx < NN) ? cur[idx] : 0;
        loc[i] = run;
        run += v;
    }
    s[t] = run;
    __syncthreads();
    for (int o = 1; o < 1024; o <<= 1) {
        const int v = (t >= o) ? s[t - o] : 0;
        __syncthreads();
        s[t] += v;
        __syncthreads();
    }
    const int excl = s[t] - run;
#pragma unroll
    for (int i = 0; i < 10; ++i) {
        const int idx = base + i;
        if (idx < NN) {
            off[idx] = excl + loc[i];
            cur[idx] = excl + loc[i];
        }
    }
    if (t == 1023) off[NN] = s[1023];
}

__global__ __launch_bounds__(256) void scatter_kernel(const int* __restrict__ ei,
                                                      int* __restrict__ cur,
                                                      int* __restrict__ perm) {
    const int e = blockIdx.x * 256 + threadIdx.x;
    if (e < EE) {
        const int p = atomicAdd(&cur[ei[EE + e]], 1);
        perm[p] = e;
    }
}

// ---------------- LN-stats quadratic form (once per call) ----------------
__global__ __launch_bounds__(256) void prep_stats(const float* __restrict__ w,
                                                  const float* __restrict__ b,
                                                  float* __restrict__ st) {
    const int t = threadIdx.x;
    const int k = t >> 4, j = t & 15;
    float acc = 0.f;
    for (int r = 0; r < D2V; ++r) acc = fmaf(w[r * DEDGE + k], w[r * DEDGE + j], acc);
    st[t] = acc * (1.f / D2V);
    if (t < DEDGE) {
        float s = 0.f, q = 0.f;
        for (int r = 0; r < D2V; ++r) {
            s += w[r * DEDGE + t];
            q = fmaf(b[r], w[r * DEDGE + t], q);
        }
        st[256 + t] = s * (1.f / D2V);
        st[272 + t] = q * (1.f / D2V);
    } else if (t == 16) {
        float s = 0.f, s2 = 0.f;
        for (int r = 0; r < D2V; ++r) {
            s += b[r];
            s2 = fmaf(b[r], b[r], s2);
        }
        st[288] = s * (1.f / D2V);
        st[289] = s2 * (1.f / D2V);
    }
}

// ---------------- A-fragment prep (once): A* = diag(g)W split hi/lo, + affine A2 ----------------
// Lane l of d-tile: row = l&31 (r = d*32+row), k-slots = (l>>5)*8 + i.
__global__ __launch_bounds__(256) void prep_afrag(const float* __restrict__ w,
                                                  const float* __restrict__ wb,
                                                  const float* __restrict__ lg,
                                                  const float* __restrict__ lb,
                                                  uint4* __restrict__ afh,
                                                  uint4* __restrict__ afl,
                                                  uint4* __restrict__ a2f) {
    const int tid = blockIdx.x * 256 + threadIdx.x;
    if (tid >= 32 * 64) return;
    const int d = tid >> 6, l = tid & 63;
    const int row = l & 31, kh = l >> 5;
    const int r = d * 32 + row;
    const float g = lg[r];
    unsigned short uh[8], ul[8];
#pragma unroll
    for (int i = 0; i < 8; ++i) {
        const float v = g * w[r * DEDGE + kh * 8 + i];
        const unsigned short h = bf16rne(v);
        uh[i] = h;
        ul[i] = bf16rne(v - bf16tof(h));
    }
    afh[d * 64 + l] = pack8(uh);
    afl[d * 64 + l] = pack8(ul);
    if (kh == 0) {
        const float bg = g * wb[r];
        const float lbv = lb[r];
        const unsigned short bgh = bf16rne(bg);
        const unsigned short bgl = bf16rne(bg - bf16tof(bgh));
        const unsigned short gh = bf16rne(g);
        const unsigned short gl = bf16rne(g - bf16tof(gh));
        const unsigned short lbh = bf16rne(lbv);
        const unsigned short lbl = bf16rne(lbv - bf16tof(lbh));
        unsigned short s[8] = {bgh, bgl, bgh, gh, gl, gh, lbh, lbl};
        a2f[d * 64 + l] = pack8(s);
    } else {
        a2f[d * 64 + l] = make_uint4(0, 0, 0, 0);
    }
}

// ---------------- per-edge stats + B-fragment prep (once) ----------------
// B col = lane&31 (edge), k-slots = (lane>>5)*8+i. B = inv*ea split hi/lo.
// B2 col: [invh, invh, invl, nmih, nmih, nmil, 1, 1] in k0..7, zeros k8..15.
__global__ __launch_bounds__(256) void stats_edge_kernel(const float* __restrict__ eattr,
                                                         const float* __restrict__ st,
                                                         uint4* __restrict__ bfh,
                                                         uint4* __restrict__ bfl,
                                                         uint4* __restrict__ b2f) {
    const int e = blockIdx.x * 256 + threadIdx.x;
    if (e >= EE) return;
    float ea[16];
    {
        const float4* ep = (const float4*)(eattr + e * DEDGE);
#pragma unroll
        for (int c = 0; c < 4; ++c) {
            const float4 t = ep[c];
            ea[4 * c] = t.x; ea[4 * c + 1] = t.y; ea[4 * c + 2] = t.z; ea[4 * c + 3] = t.w;
        }
    }
    float m = st[288];
#pragma unroll
    for (int k = 0; k < 16; ++k) m = fmaf(st[256 + k], ea[k], m);
    float ex2 = st[289];
#pragma unroll
    for (int k = 0; k < 16; ++k) {
        float t = 2.f * st[272 + k];
#pragma unroll
        for (int j = 0; j < 16; ++j) t = fmaf(st[k * 16 + j], ea[j], t);
        ex2 = fmaf(t, ea[k], ex2);
    }
    const float var = fmaxf(ex2 - m * m, 0.f);
    const float inv = rsqrtf(var + 1e-5f);
    const float nmi = -m * inv;
    const int t = e >> 5, col = e & 31;
#pragma unroll
    for (int h = 0; h < 2; ++h) {
        unsigned short uh[8], ul[8];
#pragma unroll
        for (int i = 0; i < 8; ++i) {
            const float v = inv * ea[8 * h + i];
            const unsigned short a = bf16rne(v);
            uh[i] = a;
            ul[i] = bf16rne(v - bf16tof(a));
        }
        bfh[t * 64 + h * 32 + col] = pack8(uh);
        bfl[t * 64 + h * 32 + col] = pack8(ul);
    }
    const unsigned short ivh = bf16rne(inv);
    const unsigned short ivl = bf16rne(inv - bf16tof(ivh));
    const unsigned short nmh = bf16rne(nmi);
    const unsigned short nml = bf16rne(nmi - bf16tof(nmh));
    const unsigned short one = 0x3F80;
    unsigned short s[8] = {ivh, ivh, ivl, nmh, nmh, nml, one, one};
    b2f[t * 64 + col] = pack8(s);
    b2f[t * 64 + 32 + col] = make_uint4(0, 0, 0, 0);
}

// ---------------- MFMA edge kernel (per layer): msg[e][f] ----------------
__global__ __launch_bounds__(256) void edge_mfma_kernel(
    const float* __restrict__ x, const int* __restrict__ ei,
    const uint4* __restrict__ afh, const uint4* __restrict__ afl, const uint4* __restrict__ a2f,
    const uint4* __restrict__ bfh, const uint4* __restrict__ bfl, const uint4* __restrict__ b2f,
    float* __restrict__ msgout) {
    const int lane = threadIdx.x & 63;
    const int w = (blockIdx.x * 256 + threadIdx.x) >> 6;  // tile id, 0..2499
    const int col = lane & 31, hi = lane >> 5;
    const int e = w * 32 + col;
    const int si = ei[e];
    float xr[32];
    {
        const float4* xp = (const float4*)(x + si * DD);
#pragma unroll
        for (int c = 0; c < 8; ++c) {
            const float4 t = xp[c];
            xr[4 * c] = t.x; xr[4 * c + 1] = t.y; xr[4 * c + 2] = t.z; xr[4 * c + 3] = t.w;
        }
    }
    const short8v bh = ((const short8v*)bfh)[w * 64 + lane];
    const short8v bl = ((const short8v*)bfl)[w * 64 + lane];
    const short8v b2 = ((const short8v*)b2f)[w * 64 + lane];
    float msg[16];
#pragma unroll
    for (int i = 0; i < 16; ++i) msg[i] = 0.f;
#pragma unroll
    for (int d = 0; d < 32; ++d) {
        const short8v ah = ((const short8v*)afh)[d * 64 + lane];
        const short8v al = ((const short8v*)afl)[d * 64 + lane];
        const short8v a2 = ((const short8v*)a2f)[d * 64 + lane];
        f32x16 C;
#pragma unroll
        for (int r = 0; r < 16; ++r) C[r] = 0.f;
        C = __builtin_amdgcn_mfma_f32_32x32x16_bf16(ah, bh, C, 0, 0, 0);
        C = __builtin_amdgcn_mfma_f32_32x32x16_bf16(ah, bl, C, 0, 0, 0);
        C = __builtin_amdgcn_mfma_f32_32x32x16_bf16(al, bh, C, 0, 0, 0);
        C = __builtin_amdgcn_mfma_f32_32x32x16_bf16(a2, b2, C, 0, 0, 0);
        const float xd = xr[d];
#pragma unroll
        for (int r = 0; r < 16; ++r) msg[r] = fmaf(xd, fmaxf(C[r], 0.f), msg[r]);
    }
    // f = (reg&3) + 8*(reg>>2) + 4*hi  -> contiguous float4 per reg-quad
    float* op = msgout + e * DD + hi * 4;
#pragma unroll
    for (int q = 0; q < 4; ++q)
        *(float4*)(op + q * 8) = make_float4(msg[4 * q], msg[4 * q + 1], msg[4 * q + 2], msg[4 * q + 3]);
}

// ---------------- wave-parallel node update: half-wave per node ----------------
__global__ __launch_bounds__(256) void node_wave_kernel(
    const float* __restrict__ x, const float* __restrict__ msg,
    const int* __restrict__ off, const int* __restrict__ perm,
    const float* __restrict__ root_w, const float* __restrict__ conv_b,
    const float* __restrict__ res_w, const float* __restrict__ res_b,
    const float* __restrict__ lng, const float* __restrict__ lnb,
    float* __restrict__ out) {
    const int lane = threadIdx.x & 63;
    const int w = (blockIdx.x * 256 + threadIdx.x) >> 6;  // 0..4999
    const int hi = lane >> 5, f = lane & 31;
    const int n = w * 2 + hi;
    float wrow[32];
    {
        const float4* rp = (const float4*)(root_w + f * DD);
        const float4* sp = (const float4*)(res_w + f * DD);
#pragma unroll
        for (int c = 0; c < 8; ++c) {
            const float4 a = rp[c];
            const float4 b = sp[c];
            wrow[4 * c] = a.x + b.x; wrow[4 * c + 1] = a.y + b.y;
            wrow[4 * c + 2] = a.z + b.z; wrow[4 * c + 3] = a.w + b.w;
        }
    }
    float acc = conv_b[f] + res_b[f];
    const int k0 = off[n], k1 = off[n + 1];
    for (int k = k0; k < k1; ++k) acc += msg[perm[k] * DD + f];
    const float xl = x[n * DD + f];
#pragma unroll
    for (int d = 0; d < DD; ++d) acc = fmaf(__shfl(xl, hi * 32 + d), wrow[d], acc);
    float s1 = acc, s2 = acc * acc;
#pragma unroll
    for (int o = 16; o >= 1; o >>= 1) {
        s1 += __shfl_xor(s1, o);
        s2 += __shfl_xor(s2, o);
    }
    const float m = s1 * (1.f / 32.f);
    const float v = s2 * (1.f / 32.f) - m * m;
    const float inv = rsqrtf(v + 1e-5f);
    out[n * DD + f] = fmaf((acc - m) * inv, lng[f], lnb[f]);
}

// ---------------- wave-parallel fusion head ----------------
__global__ __launch_bounds__(256) void fuse_wave_kernel(
    const float* __restrict__ o0, const float* __restrict__ o1, const float* __restrict__ o2,
    const float* __restrict__ fw, const float* __restrict__ fb,
    const float* __restrict__ g, const float* __restrict__ b,
    float* __restrict__ out) {
    const int lane = threadIdx.x & 63;
    const int w = (blockIdx.x * 256 + threadIdx.x) >> 6;
    const int hi = lane >> 5, f = lane & 31;
    const int n = w * 2 + hi;
    float fr[96];
    {
        const float4* fp = (const float4*)(fw + f * 96);
#pragma unroll
        for (int c = 0; c < 24; ++c) {
            const float4 t = fp[c];
            fr[4 * c] = t.x; fr[4 * c + 1] = t.y; fr[4 * c + 2] = t.z; fr[4 * c + 3] = t.w;
        }
    }
    float acc = fb[f];
    const float c0 = o0[n * DD + f], c1 = o1[n * DD + f], c2 = o2[n * DD + f];
#pragma unroll
    for (int d = 0; d < DD; ++d) acc = fmaf(__shfl(c0, hi * 32 + d), fr[d], acc);
#pragma unroll
    for (int d = 0; d < DD; ++d) acc = fmaf(__shfl(c1, hi * 32 + d), fr[32 + d], acc);
#pragma unroll
    for (int d = 0; d < DD; ++d) acc = fmaf(__shfl(c2, hi * 32 + d), fr[64 + d], acc);
    float s1 = acc, s2 = acc * acc;
#pragma unroll
    for (int o = 16; o >= 1; o >>= 1) {
        s1 += __shfl_xor(s1, o);
        s2 += __shfl_xor(s2, o);
    }
    const float m = s1 * (1.f / 32.f);
    const float v = s2 * (1.f / 32.f) - m * m;
    const float inv = rsqrtf(v + 1e-5f);
    out[n * DD + f] = fmaxf(fmaf((acc - m) * inv, g[f], b[f]), 0.f);
}

// ================= round-2 fallback kernels (ws too small) =================
template <bool GATHER>
__global__ __launch_bounds__(256) void edge_kernel_fb(
    const float* __restrict__ x, const int* __restrict__ ei,
    const float* __restrict__ eattr,
    const float* __restrict__ w, const float* __restrict__ wb,
    const float* __restrict__ lg, const float* __restrict__ lb,
    const float* __restrict__ st, float* __restrict__ out) {
    const int wv = threadIdx.x >> 6;
    const int lane = threadIdx.x & 63;
    const int W = blockIdx.x * 4 + wv;
    const int e = (W >> 2) * 64 + lane;
    const int f0 = (W & 3) * 8;
    const int si = ei[e];
    const int ti = ei[EE + e];
    float ea[16];
    {
        const float4* ep = (const float4*)(eattr + e * DEDGE);
#pragma unroll
        for (int c = 0; c < 4; ++c) {
            const float4 t = ep[c];
            ea[4 * c] = t.x; ea[4 * c + 1] = t.y; ea[4 * c + 2] = t.z; ea[4 * c + 3] = t.w;
        }
    }
    float m = st[288];
#pragma unroll
    for (int k = 0; k < 16; ++k) m = fmaf(st[256 + k], ea[k], m);
    float ex2 = st[289];
#pragma unroll
    for (int k = 0; k < 16; ++k) {
        float t = 2.f * st[272 + k];
#pragma unroll
        for (int j = 0; j < 16; ++j) t = fmaf(st[k * 16 + j], ea[j], t);
        ex2 = fmaf(t, ea[k], ex2);
    }
    const float var = fmaxf(ex2 - m * m, 0.f);
    const float inv = rsqrtf(var + 1e-5f);
    const float nm = -m;
    const float* xp = x + si * DD;
    float msg[8] = {0.f, 0.f, 0.f, 0.f, 0.f, 0.f, 0.f, 0.f};
#pragma unroll 1
    for (int d = 0; d < DD; ++d) {
        const float xd = xp[d];
        const int r0 = d * 32 + f0;
        const float* wr = w + r0 * DEDGE;
        const float* br = wb + r0;
        const float* gr = lg + r0;
        const float* b2r = lb + r0;
#pragma unroll
        for (int f = 0; f < 8; ++f) {
            float h = br[f];
#pragma unroll
            for (int k = 0; k < 16; ++k) h = fmaf(wr[f * 16 + k], ea[k], h);
            const float t1 = inv * gr[f];
            const float t2 = fmaf(nm, t1, b2r[f]);
            float val = fmaf(h, t1, t2);
            val = fmaxf(val, 0.f);
            msg[f] = fmaf(xd, val, msg[f]);
        }
    }
    if constexpr (GATHER) {
        float4* op = (float4*)(out + e * DD + f0);
        op[0] = make_float4(msg[0], msg[1], msg[2], msg[3]);
        op[1] = make_float4(msg[4], msg[5], msg[6], msg[7]);
    } else {
#pragma unroll
        for (int f = 0; f < 8; ++f) atomicAdd(&out[ti * DD + f0 + f], msg[f]);
    }
}

template <bool GATHER>
__global__ __launch_bounds__(256) void node_kernel_fb(
    const float* __restrict__ x, const float* __restrict__ msg,
    const int* __restrict__ off, const int* __restrict__ perm,
    const float* __restrict__ root_w, const float* __restrict__ conv_b,
    const float* __restrict__ res_w, const float* __restrict__ res_b,
    const float* __restrict__ lng, const float* __restrict__ lnb,
    float* __restrict__ out) {
    __shared__ float wsm[D2V];
    __shared__ float bs[DD], gs[DD], bbs[DD];
    for (int i = threadIdx.x; i < D2V; i += 256) wsm[i] = root_w[i] + res_w[i];
    if (threadIdx.x < DD) {
        bs[threadIdx.x] = conv_b[threadIdx.x] + res_b[threadIdx.x];
        gs[threadIdx.x] = lng[threadIdx.x];
        bbs[threadIdx.x] = lnb[threadIdx.x];
    }
    __syncthreads();
    const int n = blockIdx.x * 256 + threadIdx.x;
    if (n >= NN) return;
    float xr[DD], pre[DD];
    {
        const float4* p = (const float4*)(x + n * DD);
#pragma unroll
        for (int c = 0; c < 8; ++c) {
            const float4 t = p[c];
            xr[4 * c] = t.x; xr[4 * c + 1] = t.y; xr[4 * c + 2] = t.z; xr[4 * c + 3] = t.w;
        }
    }
    if constexpr (GATHER) {
#pragma unroll
        for (int i = 0; i < DD; ++i) pre[i] = 0.f;
        const int k1 = off[n + 1];
        for (int k = off[n]; k < k1; ++k) {
            const float4* mp = (const float4*)(msg + perm[k] * DD);
#pragma unroll
            for (int c = 0; c < 8; ++c) {
                const float4 t = mp[c];
                pre[4 * c] += t.x; pre[4 * c + 1] += t.y;
                pre[4 * c + 2] += t.z; pre[4 * c + 3] += t.w;
            }
        }
    } else {
        const float4* q = (const float4*)(msg + n * DD);
#pragma unroll
        for (int c = 0; c < 8; ++c) {
            const float4 u = q[c];
            pre[4 * c] = u.x; pre[4 * c + 1] = u.y; pre[4 * c + 2] = u.z; pre[4 * c + 3] = u.w;
        }
    }
    float s1 = 0.f, s2 = 0.f;
#pragma unroll
    for (int ff = 0; ff < DD; ++ff) {
        float acc = pre[ff] + bs[ff];
        const float* wr = wsm + ff * DD;
#pragma unroll
        for (int dd = 0; dd < DD; ++dd) acc = fmaf(xr[dd], wr[dd], acc);
        pre[ff] = acc;
        s1 += acc;
        s2 = fmaf(acc, acc, s2);
    }
    const float m = s1 * (1.f / 32.f);
    const float v = s2 * (1.f / 32.f) - m * m;
    const float inv = rsqrtf(v + 1e-5f);
    float4* op = (float4*)(out + n * DD);
#pragma unroll
    for (int c = 0; c < 8; ++c) {
        float4 t;
        t.x = fmaf((pre[4 * c + 0] - m) * inv, gs[4 * c + 0], bbs[4 * c + 0]);
        t.y = fmaf((pre[4 * c + 1] - m) * inv, gs[4 * c + 1], bbs[4 * c + 1]);
        t.z = fmaf((pre[4 * c + 2] - m) * inv, gs[4 * c + 2], bbs[4 * c + 2]);
        t.w = fmaf((pre[4 * c + 3] - m) * inv, gs[4 * c + 3], bbs[4 * c + 3]);
        op[c] = t;
    }
}

extern "C" void kernel_launch(void* const* d_in, const int* in_sizes, int n_in,
                              void* d_out, int out_size, void* d_ws, size_t ws_size,
                              hipStream_t stream) {
    const float* x   = (const float*)d_in[0];
    const int*   ei  = (const int*)d_in[1];
    const float* ea  = (const float*)d_in[2];
    const float* emw = (const float*)d_in[3];
    const float* emb = (const float*)d_in[4];
    const float* elg = (const float*)d_in[5];
    const float* elb = (const float*)d_in[6];
    const float* rootw = (const float*)d_in[7];
    const float* convb = (const float*)d_in[8];
    const float* resw  = (const float*)d_in[9];
    const float* resb  = (const float*)d_in[10];
    const float* lng   = (const float*)d_in[11];
    const float* lnb   = (const float*)d_in[12];
    const float* fw    = (const float*)d_in[13];
    const float* fb    = (const float*)d_in[14];
    const float* flg   = (const float*)d_in[15];
    const float* flb   = (const float*)d_in[16];

    // primary layout: uint4 frags first, then floats, then ints
    const size_t U4N = 2048 * 3 + NTILE * 64 * 3;          // 486144 uint4
    const size_t FR0 = U4N * 4;                            // float index of msg
    const size_t FTOT = FR0 + 2560000 + 3 * NN * DD + 320; // floats
    const size_t PRIMARY_NEED = FTOT * 4 + (size_t)(2 * (NN + 1) + EE) * 4 + 256;
    const size_t R2_NEED = (size_t)(3520320) * 4 + (size_t)(2 * (NN + 1) + EE) * 4 + 64;

    if (ws_size >= PRIMARY_NEED) {
        uint4* u4 = (uint4*)d_ws;
        uint4* afh = u4;
        uint4* afl = afh + 2048;
        uint4* a2f = afl + 2048;
        uint4* bfh = a2f + 2048;
        uint4* bfl = bfh + NTILE * 64;
        uint4* b2f = bfl + NTILE * 64;
        float* wsf = (float*)d_ws;
        float* msg  = wsf + FR0;
        float* out0 = msg + 2560000;
        float* out1 = out0 + NN * DD;
        float* out2 = out1 + NN * DD;
        float* st   = out2 + NN * DD;
        int* off  = (int*)(st + 320);
        int* cur  = off + (NN + 1);
        int* perm = cur + (NN + 1);
        float* outs[3] = {out0, out1, out2};

        hipMemsetAsync(cur, 0, (NN + 1) * sizeof(int), stream);
        hist_kernel<<<313, 256, 0, stream>>>(ei, cur);
        scan_kernel<<<1, 1024, 0, stream>>>(cur, off);
        scatter_kernel<<<313, 256, 0, stream>>>(ei, cur, perm);
        prep_stats<<<1, 256, 0, stream>>>(emw, emb, st);
        prep_afrag<<<8, 256, 0, stream>>>(emw, emb, elg, elb, afh, afl, a2f);
        stats_edge_kernel<<<313, 256, 0, stream>>>(ea, st, bfh, bfl, b2f);

        const float* xin = x;
        for (int l = 0; l < LL; ++l) {
            edge_mfma_kernel<<<625, 256, 0, stream>>>(xin, ei, afh, afl, a2f, bfh, bfl, b2f, msg);
            node_wave_kernel<<<1250, 256, 0, stream>>>(xin, msg, off, perm,
                rootw + l * D2V, convb + l * DD, resw + l * D2V, resb + l * DD,
                lng + l * DD, lnb + l * DD, outs[l]);
            xin = outs[l];
        }
        fuse_wave_kernel<<<1250, 256, 0, stream>>>(out0, out1, out2, fw, fb, flg, flb,
                                                   (float*)d_out);
    } else if (ws_size >= R2_NEED) {
        float* wsf = (float*)d_ws;
        float* msg  = wsf;
        float* out0 = wsf + 2560000;
        float* out1 = out0 + NN * DD;
        float* out2 = out1 + NN * DD;
        float* st   = wsf + 3520000;
        int* off  = (int*)(wsf + 3520320);
        int* cur  = off + (NN + 1);
        int* perm = cur + (NN + 1);
        float* outs[3] = {out0, out1, out2};

        hipMemsetAsync(cur, 0, (NN + 1) * sizeof(int), stream);
        hist_kernel<<<313, 256, 0, stream>>>(ei, cur);
        scan_kernel<<<1, 1024, 0, stream>>>(cur, off);
        scatter_kernel<<<313, 256, 0, stream>>>(ei, cur, perm);
        prep_stats<<<1, 256, 0, stream>>>(emw, emb, st);
        const float* xin = x;
        for (int l = 0; l < LL; ++l) {
            edge_kernel_fb<true><<<1250, 256, 0, stream>>>(xin, ei, ea, emw, emb, elg, elb, st, msg);
            node_kernel_fb<true><<<40, 256, 0, stream>>>(xin, msg, off, perm,
                rootw + l * D2V, convb + l * DD, resw + l * D2V, resb + l * DD,
                lng + l * DD, lnb + l * DD, outs[l]);
            xin = outs[l];
        }
        fuse_wave_kernel<<<1250, 256, 0, stream>>>(out0, out1, out2, fw, fb, flg, flb,
                                                   (float*)d_out);
    } else {
        float* wsf = (float*)d_ws;
        float* agg  = wsf;
        float* out0 = wsf + NN * DD;
        float* out1 = out0 + NN * DD;
        float* out2 = out1 + NN * DD;
        float* st   = wsf + 4 * NN * DD;
        float* outs[3] = {out0, out1, out2};

        prep_stats<<<1, 256, 0, stream>>>(emw, emb, st);
        const float* xin = x;
        for (int l = 0; l < LL; ++l) {
            hipMemsetAsync(agg, 0, NN * DD * sizeof(float), stream);
            edge_kernel_fb<false><<<1250, 256, 0, stream>>>(xin, ei, ea, emw, emb, elg, elb, st, agg);
            node_kernel_fb<false><<<40, 256, 0, stream>>>(xin, agg, nullptr, nullptr,
                rootw + l * D2V, convb + l * DD, resw + l * D2V, resb + l * DD,
                lng + l * DD, lnb + l * DD, outs[l]);
            xin = outs[l];
        }
        fuse_wave_kernel<<<1250, 256, 0, stream>>>(out0, out1, out2, fw, fb, flg, flb,
                                                   (float*)d_out);
    }
}

// Round 4
// 195.050 us; speedup vs baseline: 6.9767x; 1.3661x over previous
//
#include <hip/hip_runtime.h>

#define NN 10000
#define EE 80000
#define DD 32
#define DEDGE 16
#define LL 3
#define D2V 1024
#define NTILE 2500  // EE/32

typedef __attribute__((ext_vector_type(8))) short short8v;
typedef __attribute__((ext_vector_type(16))) float f32x16;

__device__ __forceinline__ unsigned short bf16rne(float x) {
    unsigned u = __float_as_uint(x);
    return (unsigned short)((u + 0x7FFF + ((u >> 16) & 1)) >> 16);
}
__device__ __forceinline__ float bf16tof(unsigned short h) {
    return __uint_as_float(((unsigned)h) << 16);
}
__device__ __forceinline__ uint4 pack8(const unsigned short* u) {
    uint4 r;
    r.x = (unsigned)u[0] | ((unsigned)u[1] << 16);
    r.y = (unsigned)u[2] | ((unsigned)u[3] << 16);
    r.z = (unsigned)u[4] | ((unsigned)u[5] << 16);
    r.w = (unsigned)u[6] | ((unsigned)u[7] << 16);
    return r;
}

// ---------------- CSR build (once per call) ----------------
__global__ __launch_bounds__(256) void hist_kernel(const int* __restrict__ ei, int* __restrict__ cnt) {
    const int e = blockIdx.x * 256 + threadIdx.x;
    if (e < EE) atomicAdd(&cnt[ei[EE + e]], 1);
}

__global__ __launch_bounds__(1024) void scan_kernel(int* __restrict__ cur, int* __restrict__ off) {
    __shared__ int s[1024];
    const int t = threadIdx.x;
    const int base = t * 10;
    int loc[10];
    int run = 0;
#pragma unroll
    for (int i = 0; i < 10; ++i) {
        const int idx = base + i;
        const int v = (idx < NN) ? cur[idx] : 0;
        loc[i] = run;
        run += v;
    }
    s[t] = run;
    __syncthreads();
    for (int o = 1; o < 1024; o <<= 1) {
        const int v = (t >= o) ? s[t - o] : 0;
        __syncthreads();
        s[t] += v;
        __syncthreads();
    }
    const int excl = s[t] - run;
#pragma unroll
    for (int i = 0; i < 10; ++i) {
        const int idx = base + i;
        if (idx < NN) {
            off[idx] = excl + loc[i];
            cur[idx] = excl + loc[i];
        }
    }
    if (t == 1023) off[NN] = s[1023];
}

__global__ __launch_bounds__(256) void scatter_kernel(const int* __restrict__ ei,
                                                      int* __restrict__ cur,
                                                      int* __restrict__ perm) {
    const int e = blockIdx.x * 256 + threadIdx.x;
    if (e < EE) {
        const int p = atomicAdd(&cur[ei[EE + e]], 1);
        perm[p] = e;
    }
}

// ---------------- LN-stats quadratic form (parallel over rows) ----------------
// st[0..255] M[k][j]; st[256..271] wm; st[272..287] q; st[288]=bm; st[289]=Eb2.
// 64 blocks x 16 rows each; partial sums accumulated via atomicAdd (st pre-zeroed).
__global__ __launch_bounds__(256) void prep_stats_par(const float* __restrict__ w,
                                                      const float* __restrict__ b,
                                                      float* __restrict__ st) {
    const int t = threadIdx.x;
    const int r0 = blockIdx.x * 16;
    const int k = t >> 4, j = t & 15;
    float acc = 0.f;
#pragma unroll
    for (int r = 0; r < 16; ++r)
        acc = fmaf(w[(r0 + r) * DEDGE + k], w[(r0 + r) * DEDGE + j], acc);
    atomicAdd(&st[t], acc * (1.f / D2V));
    if (t < DEDGE) {
        float s = 0.f, q = 0.f;
#pragma unroll
        for (int r = 0; r < 16; ++r) {
            s += w[(r0 + r) * DEDGE + t];
            q = fmaf(b[r0 + r], w[(r0 + r) * DEDGE + t], q);
        }
        atomicAdd(&st[256 + t], s * (1.f / D2V));
        atomicAdd(&st[272 + t], q * (1.f / D2V));
    } else if (t == 16) {
        float s = 0.f, s2 = 0.f;
#pragma unroll
        for (int r = 0; r < 16; ++r) {
            s += b[r0 + r];
            s2 = fmaf(b[r0 + r], b[r0 + r], s2);
        }
        atomicAdd(&st[288], s * (1.f / D2V));
        atomicAdd(&st[289], s2 * (1.f / D2V));
    }
}

// ---------------- A-fragment prep (once): A* = diag(g)W split hi/lo, + affine A2 ----------------
__global__ __launch_bounds__(256) void prep_afrag(const float* __restrict__ w,
                                                  const float* __restrict__ wb,
                                                  const float* __restrict__ lg,
                                                  const float* __restrict__ lb,
                                                  uint4* __restrict__ afh,
                                                  uint4* __restrict__ afl,
                                                  uint4* __restrict__ a2f) {
    const int tid = blockIdx.x * 256 + threadIdx.x;
    if (tid >= 32 * 64) return;
    const int d = tid >> 6, l = tid & 63;
    const int row = l & 31, kh = l >> 5;
    const int r = d * 32 + row;
    const float g = lg[r];
    unsigned short uh[8], ul[8];
#pragma unroll
    for (int i = 0; i < 8; ++i) {
        const float v = g * w[r * DEDGE + kh * 8 + i];
        const unsigned short h = bf16rne(v);
        uh[i] = h;
        ul[i] = bf16rne(v - bf16tof(h));
    }
    afh[d * 64 + l] = pack8(uh);
    afl[d * 64 + l] = pack8(ul);
    if (kh == 0) {
        const float bg = g * wb[r];
        const float lbv = lb[r];
        const unsigned short bgh = bf16rne(bg);
        const unsigned short bgl = bf16rne(bg - bf16tof(bgh));
        const unsigned short gh = bf16rne(g);
        const unsigned short gl = bf16rne(g - bf16tof(gh));
        const unsigned short lbh = bf16rne(lbv);
        const unsigned short lbl = bf16rne(lbv - bf16tof(lbh));
        unsigned short s[8] = {bgh, bgl, bgh, gh, gl, gh, lbh, lbl};
        a2f[d * 64 + l] = pack8(s);
    } else {
        a2f[d * 64 + l] = make_uint4(0, 0, 0, 0);
    }
}

// ---------------- per-edge stats + B-fragment prep (once) ----------------
__global__ __launch_bounds__(256) void stats_edge_kernel(const float* __restrict__ eattr,
                                                         const float* __restrict__ st,
                                                         uint4* __restrict__ bfh,
                                                         uint4* __restrict__ bfl,
                                                         uint4* __restrict__ b2f) {
    const int e = blockIdx.x * 256 + threadIdx.x;
    if (e >= EE) return;
    float ea[16];
    {
        const float4* ep = (const float4*)(eattr + e * DEDGE);
#pragma unroll
        for (int c = 0; c < 4; ++c) {
            const float4 t = ep[c];
            ea[4 * c] = t.x; ea[4 * c + 1] = t.y; ea[4 * c + 2] = t.z; ea[4 * c + 3] = t.w;
        }
    }
    float m = st[288];
#pragma unroll
    for (int k = 0; k < 16; ++k) m = fmaf(st[256 + k], ea[k], m);
    float ex2 = st[289];
#pragma unroll
    for (int k = 0; k < 16; ++k) {
        float t = 2.f * st[272 + k];
#pragma unroll
        for (int j = 0; j < 16; ++j) t = fmaf(st[k * 16 + j], ea[j], t);
        ex2 = fmaf(t, ea[k], ex2);
    }
    const float var = fmaxf(ex2 - m * m, 0.f);
    const float inv = rsqrtf(var + 1e-5f);
    const float nmi = -m * inv;
    const int t = e >> 5, col = e & 31;
#pragma unroll
    for (int h = 0; h < 2; ++h) {
        unsigned short uh[8], ul[8];
#pragma unroll
        for (int i = 0; i < 8; ++i) {
            const float v = inv * ea[8 * h + i];
            const unsigned short a = bf16rne(v);
            uh[i] = a;
            ul[i] = bf16rne(v - bf16tof(a));
        }
        bfh[t * 64 + h * 32 + col] = pack8(uh);
        bfl[t * 64 + h * 32 + col] = pack8(ul);
    }
    const unsigned short ivh = bf16rne(inv);
    const unsigned short ivl = bf16rne(inv - bf16tof(ivh));
    const unsigned short nmh = bf16rne(nmi);
    const unsigned short nml = bf16rne(nmi - bf16tof(nmh));
    const unsigned short one = 0x3F80;
    unsigned short s[8] = {ivh, ivh, ivl, nmh, nmh, nml, one, one};
    b2f[t * 64 + col] = pack8(s);
    b2f[t * 64 + 32 + col] = make_uint4(0, 0, 0, 0);
}

// ---------------- MFMA edge kernel (per layer): msg[e][f] ----------------
__global__ __launch_bounds__(256) void edge_mfma_kernel(
    const float* __restrict__ x, const int* __restrict__ ei,
    const uint4* __restrict__ afh, const uint4* __restrict__ afl, const uint4* __restrict__ a2f,
    const uint4* __restrict__ bfh, const uint4* __restrict__ bfl, const uint4* __restrict__ b2f,
    float* __restrict__ msgout) {
    const int lane = threadIdx.x & 63;
    const int w = (blockIdx.x * 256 + threadIdx.x) >> 6;  // tile id, 0..2499
    const int col = lane & 31, hi = lane >> 5;
    const int e = w * 32 + col;
    const int si = ei[e];
    float xr[32];
    {
        const float4* xp = (const float4*)(x + si * DD);
#pragma unroll
        for (int c = 0; c < 8; ++c) {
            const float4 t = xp[c];
            xr[4 * c] = t.x; xr[4 * c + 1] = t.y; xr[4 * c + 2] = t.z; xr[4 * c + 3] = t.w;
        }
    }
    const short8v bh = ((const short8v*)bfh)[w * 64 + lane];
    const short8v bl = ((const short8v*)bfl)[w * 64 + lane];
    const short8v b2 = ((const short8v*)b2f)[w * 64 + lane];
    float msg[16];
#pragma unroll
    for (int i = 0; i < 16; ++i) msg[i] = 0.f;
#pragma unroll
    for (int d = 0; d < 32; ++d) {
        const short8v ah = ((const short8v*)afh)[d * 64 + lane];
        const short8v al = ((const short8v*)afl)[d * 64 + lane];
        const short8v a2 = ((const short8v*)a2f)[d * 64 + lane];
        f32x16 C;
#pragma unroll
        for (int r = 0; r < 16; ++r) C[r] = 0.f;
        C = __builtin_amdgcn_mfma_f32_32x32x16_bf16(ah, bh, C, 0, 0, 0);
        C = __builtin_amdgcn_mfma_f32_32x32x16_bf16(ah, bl, C, 0, 0, 0);
        C = __builtin_amdgcn_mfma_f32_32x32x16_bf16(al, bh, C, 0, 0, 0);
        C = __builtin_amdgcn_mfma_f32_32x32x16_bf16(a2, b2, C, 0, 0, 0);
        const float xd = xr[d];
#pragma unroll
        for (int r = 0; r < 16; ++r) msg[r] = fmaf(xd, fmaxf(C[r], 0.f), msg[r]);
    }
    float* op = msgout + e * DD + hi * 4;
#pragma unroll
    for (int q = 0; q < 4; ++q)
        *(float4*)(op + q * 8) = make_float4(msg[4 * q], msg[4 * q + 1], msg[4 * q + 2], msg[4 * q + 3]);
}

// ---------------- wave-parallel node update: half-wave per node ----------------
__global__ __launch_bounds__(256) void node_wave_kernel(
    const float* __restrict__ x, const float* __restrict__ msg,
    const int* __restrict__ off, const int* __restrict__ perm,
    const float* __restrict__ root_w, const float* __restrict__ conv_b,
    const float* __restrict__ res_w, const float* __restrict__ res_b,
    const float* __restrict__ lng, const float* __restrict__ lnb,
    float* __restrict__ out) {
    const int lane = threadIdx.x & 63;
    const int w = (blockIdx.x * 256 + threadIdx.x) >> 6;  // 0..4999
    const int hi = lane >> 5, f = lane & 31;
    const int n = w * 2 + hi;
    float wrow[32];
    {
        const float4* rp = (const float4*)(root_w + f * DD);
        const float4* sp = (const float4*)(res_w + f * DD);
#pragma unroll
        for (int c = 0; c < 8; ++c) {
            const float4 a = rp[c];
            const float4 b = sp[c];
            wrow[4 * c] = a.x + b.x; wrow[4 * c + 1] = a.y + b.y;
            wrow[4 * c + 2] = a.z + b.z; wrow[4 * c + 3] = a.w + b.w;
        }
    }
    float acc = conv_b[f] + res_b[f];
    const int k0 = off[n], k1 = off[n + 1];
    for (int k = k0; k < k1; ++k) acc += msg[perm[k] * DD + f];
    const float xl = x[n * DD + f];
#pragma unroll
    for (int d = 0; d < DD; ++d) acc = fmaf(__shfl(xl, hi * 32 + d), wrow[d], acc);
    float s1 = acc, s2 = acc * acc;
#pragma unroll
    for (int o = 16; o >= 1; o >>= 1) {
        s1 += __shfl_xor(s1, o);
        s2 += __shfl_xor(s2, o);
    }
    const float m = s1 * (1.f / 32.f);
    const float v = s2 * (1.f / 32.f) - m * m;
    const float inv = rsqrtf(v + 1e-5f);
    out[n * DD + f] = fmaf((acc - m) * inv, lng[f], lnb[f]);
}

// ---------------- wave-parallel fusion head ----------------
__global__ __launch_bounds__(256) void fuse_wave_kernel(
    const float* __restrict__ o0, const float* __restrict__ o1, const float* __restrict__ o2,
    const float* __restrict__ fw, const float* __restrict__ fb,
    const float* __restrict__ g, const float* __restrict__ b,
    float* __restrict__ out) {
    const int lane = threadIdx.x & 63;
    const int w = (blockIdx.x * 256 + threadIdx.x) >> 6;
    const int hi = lane >> 5, f = lane & 31;
    const int n = w * 2 + hi;
    float fr[96];
    {
        const float4* fp = (const float4*)(fw + f * 96);
#pragma unroll
        for (int c = 0; c < 24; ++c) {
            const float4 t = fp[c];
            fr[4 * c] = t.x; fr[4 * c + 1] = t.y; fr[4 * c + 2] = t.z; fr[4 * c + 3] = t.w;
        }
    }
    float acc = fb[f];
    const float c0 = o0[n * DD + f], c1 = o1[n * DD + f], c2 = o2[n * DD + f];
#pragma unroll
    for (int d = 0; d < DD; ++d) acc = fmaf(__shfl(c0, hi * 32 + d), fr[d], acc);
#pragma unroll
    for (int d = 0; d < DD; ++d) acc = fmaf(__shfl(c1, hi * 32 + d), fr[32 + d], acc);
#pragma unroll
    for (int d = 0; d < DD; ++d) acc = fmaf(__shfl(c2, hi * 32 + d), fr[64 + d], acc);
    float s1 = acc, s2 = acc * acc;
#pragma unroll
    for (int o = 16; o >= 1; o >>= 1) {
        s1 += __shfl_xor(s1, o);
        s2 += __shfl_xor(s2, o);
    }
    const float m = s1 * (1.f / 32.f);
    const float v = s2 * (1.f / 32.f) - m * m;
    const float inv = rsqrtf(v + 1e-5f);
    out[n * DD + f] = fmaxf(fmaf((acc - m) * inv, g[f], b[f]), 0.f);
}

// ================= fallback kernels (ws too small) =================
template <bool GATHER>
__global__ __launch_bounds__(256) void edge_kernel_fb(
    const float* __restrict__ x, const int* __restrict__ ei,
    const float* __restrict__ eattr,
    const float* __restrict__ w, const float* __restrict__ wb,
    const float* __restrict__ lg, const float* __restrict__ lb,
    const float* __restrict__ st, float* __restrict__ out) {
    const int wv = threadIdx.x >> 6;
    const int lane = threadIdx.x & 63;
    const int W = blockIdx.x * 4 + wv;
    const int e = (W >> 2) * 64 + lane;
    const int f0 = (W & 3) * 8;
    const int si = ei[e];
    const int ti = ei[EE + e];
    float ea[16];
    {
        const float4* ep = (const float4*)(eattr + e * DEDGE);
#pragma unroll
        for (int c = 0; c < 4; ++c) {
            const float4 t = ep[c];
            ea[4 * c] = t.x; ea[4 * c + 1] = t.y; ea[4 * c + 2] = t.z; ea[4 * c + 3] = t.w;
        }
    }
    float m = st[288];
#pragma unroll
    for (int k = 0; k < 16; ++k) m = fmaf(st[256 + k], ea[k], m);
    float ex2 = st[289];
#pragma unroll
    for (int k = 0; k < 16; ++k) {
        float t = 2.f * st[272 + k];
#pragma unroll
        for (int j = 0; j < 16; ++j) t = fmaf(st[k * 16 + j], ea[j], t);
        ex2 = fmaf(t, ea[k], ex2);
    }
    const float var = fmaxf(ex2 - m * m, 0.f);
    const float inv = rsqrtf(var + 1e-5f);
    const float nm = -m;
    const float* xp = x + si * DD;
    float msg[8] = {0.f, 0.f, 0.f, 0.f, 0.f, 0.f, 0.f, 0.f};
#pragma unroll 1
    for (int d = 0; d < DD; ++d) {
        const float xd = xp[d];
        const int r0 = d * 32 + f0;
        const float* wr = w + r0 * DEDGE;
        const float* br = wb + r0;
        const float* gr = lg + r0;
        const float* b2r = lb + r0;
#pragma unroll
        for (int f = 0; f < 8; ++f) {
            float h = br[f];
#pragma unroll
            for (int k = 0; k < 16; ++k) h = fmaf(wr[f * 16 + k], ea[k], h);
            const float t1 = inv * gr[f];
            const float t2 = fmaf(nm, t1, b2r[f]);
            float val = fmaf(h, t1, t2);
            val = fmaxf(val, 0.f);
            msg[f] = fmaf(xd, val, msg[f]);
        }
    }
    if constexpr (GATHER) {
        float4* op = (float4*)(out + e * DD + f0);
        op[0] = make_float4(msg[0], msg[1], msg[2], msg[3]);
        op[1] = make_float4(msg[4], msg[5], msg[6], msg[7]);
    } else {
#pragma unroll
        for (int f = 0; f < 8; ++f) atomicAdd(&out[ti * DD + f0 + f], msg[f]);
    }
}

template <bool GATHER>
__global__ __launch_bounds__(256) void node_kernel_fb(
    const float* __restrict__ x, const float* __restrict__ msg,
    const int* __restrict__ off, const int* __restrict__ perm,
    const float* __restrict__ root_w, const float* __restrict__ conv_b,
    const float* __restrict__ res_w, const float* __restrict__ res_b,
    const float* __restrict__ lng, const float* __restrict__ lnb,
    float* __restrict__ out) {
    __shared__ float wsm[D2V];
    __shared__ float bs[DD], gs[DD], bbs[DD];
    for (int i = threadIdx.x; i < D2V; i += 256) wsm[i] = root_w[i] + res_w[i];
    if (threadIdx.x < DD) {
        bs[threadIdx.x] = conv_b[threadIdx.x] + res_b[threadIdx.x];
        gs[threadIdx.x] = lng[threadIdx.x];
        bbs[threadIdx.x] = lnb[threadIdx.x];
    }
    __syncthreads();
    const int n = blockIdx.x * 256 + threadIdx.x;
    if (n >= NN) return;
    float xr[DD], pre[DD];
    {
        const float4* p = (const float4*)(x + n * DD);
#pragma unroll
        for (int c = 0; c < 8; ++c) {
            const float4 t = p[c];
            xr[4 * c] = t.x; xr[4 * c + 1] = t.y; xr[4 * c + 2] = t.z; xr[4 * c + 3] = t.w;
        }
    }
    if constexpr (GATHER) {
#pragma unroll
        for (int i = 0; i < DD; ++i) pre[i] = 0.f;
        const int k1 = off[n + 1];
        for (int k = off[n]; k < k1; ++k) {
            const float4* mp = (const float4*)(msg + perm[k] * DD);
#pragma unroll
            for (int c = 0; c < 8; ++c) {
                const float4 t = mp[c];
                pre[4 * c] += t.x; pre[4 * c + 1] += t.y;
                pre[4 * c + 2] += t.z; pre[4 * c + 3] += t.w;
            }
        }
    } else {
        const float4* q = (const float4*)(msg + n * DD);
#pragma unroll
        for (int c = 0; c < 8; ++c) {
            const float4 u = q[c];
            pre[4 * c] = u.x; pre[4 * c + 1] = u.y; pre[4 * c + 2] = u.z; pre[4 * c + 3] = u.w;
        }
    }
    float s1 = 0.f, s2 = 0.f;
#pragma unroll
    for (int ff = 0; ff < DD; ++ff) {
        float acc = pre[ff] + bs[ff];
        const float* wr = wsm + ff * DD;
#pragma unroll
        for (int dd = 0; dd < DD; ++dd) acc = fmaf(xr[dd], wr[dd], acc);
        pre[ff] = acc;
        s1 += acc;
        s2 = fmaf(acc, acc, s2);
    }
    const float m = s1 * (1.f / 32.f);
    const float v = s2 * (1.f / 32.f) - m * m;
    const float inv = rsqrtf(v + 1e-5f);
    float4* op = (float4*)(out + n * DD);
#pragma unroll
    for (int c = 0; c < 8; ++c) {
        float4 t;
        t.x = fmaf((pre[4 * c + 0] - m) * inv, gs[4 * c + 0], bbs[4 * c + 0]);
        t.y = fmaf((pre[4 * c + 1] - m) * inv, gs[4 * c + 1], bbs[4 * c + 1]);
        t.z = fmaf((pre[4 * c + 2] - m) * inv, gs[4 * c + 2], bbs[4 * c + 2]);
        t.w = fmaf((pre[4 * c + 3] - m) * inv, gs[4 * c + 3], bbs[4 * c + 3]);
        op[c] = t;
    }
}

extern "C" void kernel_launch(void* const* d_in, const int* in_sizes, int n_in,
                              void* d_out, int out_size, void* d_ws, size_t ws_size,
                              hipStream_t stream) {
    const float* x   = (const float*)d_in[0];
    const int*   ei  = (const int*)d_in[1];
    const float* ea  = (const float*)d_in[2];
    const float* emw = (const float*)d_in[3];
    const float* emb = (const float*)d_in[4];
    const float* elg = (const float*)d_in[5];
    const float* elb = (const float*)d_in[6];
    const float* rootw = (const float*)d_in[7];
    const float* convb = (const float*)d_in[8];
    const float* resw  = (const float*)d_in[9];
    const float* resb  = (const float*)d_in[10];
    const float* lng   = (const float*)d_in[11];
    const float* lnb   = (const float*)d_in[12];
    const float* fw    = (const float*)d_in[13];
    const float* fb    = (const float*)d_in[14];
    const float* flg   = (const float*)d_in[15];
    const float* flb   = (const float*)d_in[16];

    // primary layout: uint4 frags first, then floats, then ints
    const size_t U4N = 2048 * 3 + NTILE * 64 * 3;          // 486144 uint4
    const size_t FR0 = U4N * 4;                            // float index of msg
    const size_t FTOT = FR0 + 2560000 + 3 * NN * DD + 320; // floats
    const size_t PRIMARY_NEED = FTOT * 4 + (size_t)(2 * (NN + 1) + EE) * 4 + 256;
    const size_t R2_NEED = (size_t)(3520320) * 4 + (size_t)(2 * (NN + 1) + EE) * 4 + 64;

    if (ws_size >= PRIMARY_NEED) {
        uint4* u4 = (uint4*)d_ws;
        uint4* afh = u4;
        uint4* afl = afh + 2048;
        uint4* a2f = afl + 2048;
        uint4* bfh = a2f + 2048;
        uint4* bfl = bfh + NTILE * 64;
        uint4* b2f = bfl + NTILE * 64;
        float* wsf = (float*)d_ws;
        float* msg  = wsf + FR0;
        float* out0 = msg + 2560000;
        float* out1 = out0 + NN * DD;
        float* out2 = out1 + NN * DD;
        float* st   = out2 + NN * DD;
        int* off  = (int*)(st + 320);
        int* cur  = off + (NN + 1);
        int* perm = cur + (NN + 1);
        float* outs[3] = {out0, out1, out2};

        hipMemsetAsync(cur, 0, (NN + 1) * sizeof(int), stream);
        hipMemsetAsync(st, 0, 320 * sizeof(float), stream);
        hist_kernel<<<313, 256, 0, stream>>>(ei, cur);
        scan_kernel<<<1, 1024, 0, stream>>>(cur, off);
        scatter_kernel<<<313, 256, 0, stream>>>(ei, cur, perm);
        prep_stats_par<<<64, 256, 0, stream>>>(emw, emb, st);
        prep_afrag<<<8, 256, 0, stream>>>(emw, emb, elg, elb, afh, afl, a2f);
        stats_edge_kernel<<<313, 256, 0, stream>>>(ea, st, bfh, bfl, b2f);

        const float* xin = x;
        for (int l = 0; l < LL; ++l) {
            edge_mfma_kernel<<<625, 256, 0, stream>>>(xin, ei, afh, afl, a2f, bfh, bfl, b2f, msg);
            node_wave_kernel<<<1250, 256, 0, stream>>>(xin, msg, off, perm,
                rootw + l * D2V, convb + l * DD, resw + l * D2V, resb + l * DD,
                lng + l * DD, lnb + l * DD, outs[l]);
            xin = outs[l];
        }
        fuse_wave_kernel<<<1250, 256, 0, stream>>>(out0, out1, out2, fw, fb, flg, flb,
                                                   (float*)d_out);
    } else if (ws_size >= R2_NEED) {
        float* wsf = (float*)d_ws;
        float* msg  = wsf;
        float* out0 = wsf + 2560000;
        float* out1 = out0 + NN * DD;
        float* out2 = out1 + NN * DD;
        float* st   = wsf + 3520000;
        int* off  = (int*)(wsf + 3520320);
        int* cur  = off + (NN + 1);
        int* perm = cur + (NN + 1);
        float* outs[3] = {out0, out1, out2};

        hipMemsetAsync(cur, 0, (NN + 1) * sizeof(int), stream);
        hipMemsetAsync(st, 0, 320 * sizeof(float), stream);
        hist_kernel<<<313, 256, 0, stream>>>(ei, cur);
        scan_kernel<<<1, 1024, 0, stream>>>(cur, off);
        scatter_kernel<<<313, 256, 0, stream>>>(ei, cur, perm);
        prep_stats_par<<<64, 256, 0, stream>>>(emw, emb, st);
        const float* xin = x;
        for (int l = 0; l < LL; ++l) {
            edge_kernel_fb<true><<<1250, 256, 0, stream>>>(xin, ei, ea, emw, emb, elg, elb, st, msg);
            node_kernel_fb<true><<<40, 256, 0, stream>>>(xin, msg, off, perm,
                rootw + l * D2V, convb + l * DD, resw + l * D2V, resb + l * DD,
                lng + l * DD, lnb + l * DD, outs[l]);
            xin = outs[l];
        }
        fuse_wave_kernel<<<1250, 256, 0, stream>>>(out0, out1, out2, fw, fb, flg, flb,
                                                   (float*)d_out);
    } else {
        float* wsf = (float*)d_ws;
        float* agg  = wsf;
        float* out0 = wsf + NN * DD;
        float* out1 = out0 + NN * DD;
        float* out2 = out1 + NN * DD;
        float* st   = wsf + 4 * NN * DD;
        float* outs[3] = {out0, out1, out2};

        hipMemsetAsync(st, 0, 320 * sizeof(float), stream);
        prep_stats_par<<<64, 256, 0, stream>>>(emw, emb, st);
        const float* xin = x;
        for (int l = 0; l < LL; ++l) {
            hipMemsetAsync(agg, 0, NN * DD * sizeof(float), stream);
            edge_kernel_fb<false><<<1250, 256, 0, stream>>>(xin, ei, ea, emw, emb, elg, elb, st, agg);
            node_kernel_fb<false><<<40, 256, 0, stream>>>(xin, agg, nullptr, nullptr,
                rootw + l * D2V, convb + l * DD, resw + l * D2V, resb + l * DD,
                lng + l * DD, lnb + l * DD, outs[l]);
            xin = outs[l];
        }
        fuse_wave_kernel<<<1250, 256, 0, stream>>>(out0, out1, out2, fw, fb, flg, flb,
                                                   (float*)d_out);
    }
}

// Round 5
// 172.823 us; speedup vs baseline: 7.8739x; 1.1286x over previous
//
#include <hip/hip_runtime.h>

#define NN 10000
#define EE 80000
#define DD 32
#define DEDGE 16
#define LL 3
#define D2V 1024
#define NTILE 2500  // EE/32

typedef __attribute__((ext_vector_type(8))) short short8v;
typedef __attribute__((ext_vector_type(16))) float f32x16;

__device__ __forceinline__ unsigned short bf16rne(float x) {
    unsigned u = __float_as_uint(x);
    return (unsigned short)((u + 0x7FFF + ((u >> 16) & 1)) >> 16);
}
__device__ __forceinline__ float bf16tof(unsigned short h) {
    return __uint_as_float(((unsigned)h) << 16);
}
__device__ __forceinline__ uint4 pack8(const unsigned short* u) {
    uint4 r;
    r.x = (unsigned)u[0] | ((unsigned)u[1] << 16);
    r.y = (unsigned)u[2] | ((unsigned)u[3] << 16);
    r.z = (unsigned)u[4] | ((unsigned)u[5] << 16);
    r.w = (unsigned)u[6] | ((unsigned)u[7] << 16);
    return r;
}

// ---------------- merged setup kernel ----------------
// blocks [0,313): hist of targets into cur (pre-zeroed)
// blocks [313,377): LN quadratic-form partials into st (pre-zeroed)
// blocks [377,385): A-fragment prep
__global__ __launch_bounds__(256) void setup1_kernel(
    const int* __restrict__ ei,
    const float* __restrict__ w, const float* __restrict__ wb,
    const float* __restrict__ lg, const float* __restrict__ lb,
    int* __restrict__ cnt, float* __restrict__ st,
    uint4* __restrict__ afh, uint4* __restrict__ afl, uint4* __restrict__ a2f) {
    const int bid = blockIdx.x;
    const int t = threadIdx.x;
    if (bid < 313) {
        const int e = bid * 256 + t;
        if (e < EE) atomicAdd(&cnt[ei[EE + e]], 1);
    } else if (bid < 377) {
        const int r0 = (bid - 313) * 16;
        const int k = t >> 4, j = t & 15;
        float acc = 0.f;
#pragma unroll
        for (int r = 0; r < 16; ++r)
            acc = fmaf(w[(r0 + r) * DEDGE + k], w[(r0 + r) * DEDGE + j], acc);
        atomicAdd(&st[t], acc * (1.f / D2V));
        if (t < DEDGE) {
            float s = 0.f, q = 0.f;
#pragma unroll
            for (int r = 0; r < 16; ++r) {
                s += w[(r0 + r) * DEDGE + t];
                q = fmaf(wb[r0 + r], w[(r0 + r) * DEDGE + t], q);
            }
            atomicAdd(&st[256 + t], s * (1.f / D2V));
            atomicAdd(&st[272 + t], q * (1.f / D2V));
        } else if (t == 16) {
            float s = 0.f, s2 = 0.f;
#pragma unroll
            for (int r = 0; r < 16; ++r) {
                s += wb[r0 + r];
                s2 = fmaf(wb[r0 + r], wb[r0 + r], s2);
            }
            atomicAdd(&st[288], s * (1.f / D2V));
            atomicAdd(&st[289], s2 * (1.f / D2V));
        }
    } else {
        const int tid = (bid - 377) * 256 + t;
        if (tid >= 32 * 64) return;
        const int d = tid >> 6, l = tid & 63;
        const int row = l & 31, kh = l >> 5;
        const int r = d * 32 + row;
        const float g = lg[r];
        unsigned short uh[8], ul[8];
#pragma unroll
        for (int i = 0; i < 8; ++i) {
            const float v = g * w[r * DEDGE + kh * 8 + i];
            const unsigned short h = bf16rne(v);
            uh[i] = h;
            ul[i] = bf16rne(v - bf16tof(h));
        }
        afh[d * 64 + l] = pack8(uh);
        afl[d * 64 + l] = pack8(ul);
        if (kh == 0) {
            const float bg = g * wb[r];
            const float lbv = lb[r];
            const unsigned short bgh = bf16rne(bg);
            const unsigned short bgl = bf16rne(bg - bf16tof(bgh));
            const unsigned short gh = bf16rne(g);
            const unsigned short gl = bf16rne(g - bf16tof(gh));
            const unsigned short lbh = bf16rne(lbv);
            const unsigned short lbl = bf16rne(lbv - bf16tof(lbh));
            unsigned short s[8] = {bgh, bgl, bgh, gh, gl, gh, lbh, lbl};
            a2f[d * 64 + l] = pack8(s);
        } else {
            a2f[d * 64 + l] = make_uint4(0, 0, 0, 0);
        }
    }
}

__global__ __launch_bounds__(1024) void scan_kernel(int* __restrict__ cur, int* __restrict__ off) {
    __shared__ int s[1024];
    const int t = threadIdx.x;
    const int base = t * 10;
    int loc[10];
    int run = 0;
#pragma unroll
    for (int i = 0; i < 10; ++i) {
        const int idx = base + i;
        const int v = (idx < NN) ? cur[idx] : 0;
        loc[i] = run;
        run += v;
    }
    s[t] = run;
    __syncthreads();
    for (int o = 1; o < 1024; o <<= 1) {
        const int v = (t >= o) ? s[t - o] : 0;
        __syncthreads();
        s[t] += v;
        __syncthreads();
    }
    const int excl = s[t] - run;
#pragma unroll
    for (int i = 0; i < 10; ++i) {
        const int idx = base + i;
        if (idx < NN) {
            off[idx] = excl + loc[i];
            cur[idx] = excl + loc[i];
        }
    }
    if (t == 1023) off[NN] = s[1023];
}

__global__ __launch_bounds__(256) void scatter_kernel(const int* __restrict__ ei,
                                                      int* __restrict__ cur,
                                                      int* __restrict__ perm) {
    const int e = blockIdx.x * 256 + threadIdx.x;
    if (e < EE) {
        const int p = atomicAdd(&cur[ei[EE + e]], 1);
        perm[p] = e;
    }
}

// ---------------- per-position stats + B-fragment prep (perm order) ----------------
__global__ __launch_bounds__(256) void stats_edge_perm(const float* __restrict__ eattr,
                                                       const float* __restrict__ st,
                                                       const int* __restrict__ perm,
                                                       const int* __restrict__ ei,
                                                       uint4* __restrict__ bfh,
                                                       uint4* __restrict__ bfl,
                                                       uint4* __restrict__ b2f,
                                                       int* __restrict__ sperm) {
    const int p = blockIdx.x * 256 + threadIdx.x;
    if (p >= EE) return;
    const int e = perm[p];
    sperm[p] = ei[e];
    float ea[16];
    {
        const float4* ep = (const float4*)(eattr + e * DEDGE);
#pragma unroll
        for (int c = 0; c < 4; ++c) {
            const float4 t = ep[c];
            ea[4 * c] = t.x; ea[4 * c + 1] = t.y; ea[4 * c + 2] = t.z; ea[4 * c + 3] = t.w;
        }
    }
    float m = st[288];
#pragma unroll
    for (int k = 0; k < 16; ++k) m = fmaf(st[256 + k], ea[k], m);
    float ex2 = st[289];
#pragma unroll
    for (int k = 0; k < 16; ++k) {
        float t = 2.f * st[272 + k];
#pragma unroll
        for (int j = 0; j < 16; ++j) t = fmaf(st[k * 16 + j], ea[j], t);
        ex2 = fmaf(t, ea[k], ex2);
    }
    const float var = fmaxf(ex2 - m * m, 0.f);
    const float inv = rsqrtf(var + 1e-5f);
    const float nmi = -m * inv;
    const int t = p >> 5, col = p & 31;
#pragma unroll
    for (int h = 0; h < 2; ++h) {
        unsigned short uh[8], ul[8];
#pragma unroll
        for (int i = 0; i < 8; ++i) {
            const float v = inv * ea[8 * h + i];
            const unsigned short a = bf16rne(v);
            uh[i] = a;
            ul[i] = bf16rne(v - bf16tof(a));
        }
        bfh[t * 64 + h * 32 + col] = pack8(uh);
        bfl[t * 64 + h * 32 + col] = pack8(ul);
    }
    const unsigned short ivh = bf16rne(inv);
    const unsigned short ivl = bf16rne(inv - bf16tof(ivh));
    const unsigned short nmh = bf16rne(nmi);
    const unsigned short nml = bf16rne(nmi - bf16tof(nmh));
    const unsigned short one = 0x3F80;
    unsigned short s[8] = {ivh, ivh, ivl, nmh, nmh, nml, one, one};
    b2f[t * 64 + col] = pack8(s);
    b2f[t * 64 + 32 + col] = make_uint4(0, 0, 0, 0);
}

// ---------------- MFMA edge kernel (per layer): msg at permuted position ----------------
__global__ __launch_bounds__(256) void edge_mfma_kernel(
    const float* __restrict__ x, const int* __restrict__ sperm,
    const uint4* __restrict__ afh, const uint4* __restrict__ afl, const uint4* __restrict__ a2f,
    const uint4* __restrict__ bfh, const uint4* __restrict__ bfl, const uint4* __restrict__ b2f,
    float* __restrict__ msgout) {
    const int lane = threadIdx.x & 63;
    const int w = (blockIdx.x * 256 + threadIdx.x) >> 6;  // tile id, 0..2499
    const int col = lane & 31, hi = lane >> 5;
    const int p = w * 32 + col;
    const int si = sperm[p];
    float xr[32];
    {
        const float4* xp = (const float4*)(x + si * DD);
#pragma unroll
        for (int c = 0; c < 8; ++c) {
            const float4 t = xp[c];
            xr[4 * c] = t.x; xr[4 * c + 1] = t.y; xr[4 * c + 2] = t.z; xr[4 * c + 3] = t.w;
        }
    }
    const short8v bh = ((const short8v*)bfh)[w * 64 + lane];
    const short8v bl = ((const short8v*)bfl)[w * 64 + lane];
    const short8v b2 = ((const short8v*)b2f)[w * 64 + lane];
    float msg[16];
#pragma unroll
    for (int i = 0; i < 16; ++i) msg[i] = 0.f;
#pragma unroll
    for (int d = 0; d < 32; ++d) {
        const short8v ah = ((const short8v*)afh)[d * 64 + lane];
        const short8v al = ((const short8v*)afl)[d * 64 + lane];
        const short8v a2 = ((const short8v*)a2f)[d * 64 + lane];
        f32x16 C;
#pragma unroll
        for (int r = 0; r < 16; ++r) C[r] = 0.f;
        C = __builtin_amdgcn_mfma_f32_32x32x16_bf16(ah, bh, C, 0, 0, 0);
        C = __builtin_amdgcn_mfma_f32_32x32x16_bf16(ah, bl, C, 0, 0, 0);
        C = __builtin_amdgcn_mfma_f32_32x32x16_bf16(al, bh, C, 0, 0, 0);
        C = __builtin_amdgcn_mfma_f32_32x32x16_bf16(a2, b2, C, 0, 0, 0);
        const float xd = xr[d];
#pragma unroll
        for (int r = 0; r < 16; ++r) msg[r] = fmaf(xd, fmaxf(C[r], 0.f), msg[r]);
    }
    float* op = msgout + p * DD + hi * 4;
#pragma unroll
    for (int q = 0; q < 4; ++q)
        *(float4*)(op + q * 8) = make_float4(msg[4 * q], msg[4 * q + 1], msg[4 * q + 2], msg[4 * q + 3]);
}

// ---------------- node update, sequential msg gather (layers 0,1) ----------------
__global__ __launch_bounds__(256) void node_wave_kernel(
    const float* __restrict__ x, const float* __restrict__ msg,
    const int* __restrict__ off,
    const float* __restrict__ root_w, const float* __restrict__ conv_b,
    const float* __restrict__ res_w, const float* __restrict__ res_b,
    const float* __restrict__ lng, const float* __restrict__ lnb,
    float* __restrict__ out) {
    const int lane = threadIdx.x & 63;
    const int w = (blockIdx.x * 256 + threadIdx.x) >> 6;  // 0..4999
    const int hi = lane >> 5, f = lane & 31;
    const int n = w * 2 + hi;
    float wrow[32];
    {
        const float4* rp = (const float4*)(root_w + f * DD);
        const float4* sp = (const float4*)(res_w + f * DD);
#pragma unroll
        for (int c = 0; c < 8; ++c) {
            const float4 a = rp[c];
            const float4 b = sp[c];
            wrow[4 * c] = a.x + b.x; wrow[4 * c + 1] = a.y + b.y;
            wrow[4 * c + 2] = a.z + b.z; wrow[4 * c + 3] = a.w + b.w;
        }
    }
    float acc = conv_b[f] + res_b[f];
    const int k0 = off[n], k1 = off[n + 1];
    for (int k = k0; k < k1; ++k) acc += msg[k * DD + f];
    const float xl = x[n * DD + f];
#pragma unroll
    for (int d = 0; d < DD; ++d) acc = fmaf(__shfl(xl, hi * 32 + d), wrow[d], acc);
    float s1 = acc, s2 = acc * acc;
#pragma unroll
    for (int o = 16; o >= 1; o >>= 1) {
        s1 += __shfl_xor(s1, o);
        s2 += __shfl_xor(s2, o);
    }
    const float m = s1 * (1.f / 32.f);
    const float v = s2 * (1.f / 32.f) - m * m;
    const float inv = rsqrtf(v + 1e-5f);
    out[n * DD + f] = fmaf((acc - m) * inv, lng[f], lnb[f]);
}

// ---------------- layer-2 node update fused with fusion head ----------------
__global__ __launch_bounds__(256) void node_fuse_kernel(
    const float* __restrict__ x, const float* __restrict__ msg,
    const int* __restrict__ off,
    const float* __restrict__ root_w, const float* __restrict__ conv_b,
    const float* __restrict__ res_w, const float* __restrict__ res_b,
    const float* __restrict__ lng, const float* __restrict__ lnb,
    const float* __restrict__ o0, const float* __restrict__ o1,
    const float* __restrict__ fw, const float* __restrict__ fb,
    const float* __restrict__ fg, const float* __restrict__ fbb,
    float* __restrict__ out) {
    const int lane = threadIdx.x & 63;
    const int w = (blockIdx.x * 256 + threadIdx.x) >> 6;
    const int hi = lane >> 5, f = lane & 31;
    const int n = w * 2 + hi;
    float o2v;
    {
        float wrow[32];
        {
            const float4* rp = (const float4*)(root_w + f * DD);
            const float4* sp = (const float4*)(res_w + f * DD);
#pragma unroll
            for (int c = 0; c < 8; ++c) {
                const float4 a = rp[c];
                const float4 b = sp[c];
                wrow[4 * c] = a.x + b.x; wrow[4 * c + 1] = a.y + b.y;
                wrow[4 * c + 2] = a.z + b.z; wrow[4 * c + 3] = a.w + b.w;
            }
        }
        float acc = conv_b[f] + res_b[f];
        const int k0 = off[n], k1 = off[n + 1];
        for (int k = k0; k < k1; ++k) acc += msg[k * DD + f];
        const float xl = x[n * DD + f];
#pragma unroll
        for (int d = 0; d < DD; ++d) acc = fmaf(__shfl(xl, hi * 32 + d), wrow[d], acc);
        float s1 = acc, s2 = acc * acc;
#pragma unroll
        for (int o = 16; o >= 1; o >>= 1) {
            s1 += __shfl_xor(s1, o);
            s2 += __shfl_xor(s2, o);
        }
        const float m = s1 * (1.f / 32.f);
        const float v = s2 * (1.f / 32.f) - m * m;
        const float inv = rsqrtf(v + 1e-5f);
        o2v = fmaf((acc - m) * inv, lng[f], lnb[f]);
    }
    float fr[96];
    {
        const float4* fp = (const float4*)(fw + f * 96);
#pragma unroll
        for (int c = 0; c < 24; ++c) {
            const float4 t = fp[c];
            fr[4 * c] = t.x; fr[4 * c + 1] = t.y; fr[4 * c + 2] = t.z; fr[4 * c + 3] = t.w;
        }
    }
    float acc = fb[f];
    const float c0 = o0[n * DD + f], c1 = o1[n * DD + f];
#pragma unroll
    for (int d = 0; d < DD; ++d) acc = fmaf(__shfl(c0, hi * 32 + d), fr[d], acc);
#pragma unroll
    for (int d = 0; d < DD; ++d) acc = fmaf(__shfl(c1, hi * 32 + d), fr[32 + d], acc);
#pragma unroll
    for (int d = 0; d < DD; ++d) acc = fmaf(__shfl(o2v, hi * 32 + d), fr[64 + d], acc);
    float s1 = acc, s2 = acc * acc;
#pragma unroll
    for (int o = 16; o >= 1; o >>= 1) {
        s1 += __shfl_xor(s1, o);
        s2 += __shfl_xor(s2, o);
    }
    const float m = s1 * (1.f / 32.f);
    const float v = s2 * (1.f / 32.f) - m * m;
    const float inv = rsqrtf(v + 1e-5f);
    out[n * DD + f] = fmaxf(fmaf((acc - m) * inv, fg[f], fbb[f]), 0.f);
}

// ---------------- standalone fusion head (fallback path) ----------------
__global__ __launch_bounds__(256) void fuse_wave_kernel(
    const float* __restrict__ o0, const float* __restrict__ o1, const float* __restrict__ o2,
    const float* __restrict__ fw, const float* __restrict__ fb,
    const float* __restrict__ g, const float* __restrict__ b,
    float* __restrict__ out) {
    const int lane = threadIdx.x & 63;
    const int w = (blockIdx.x * 256 + threadIdx.x) >> 6;
    const int hi = lane >> 5, f = lane & 31;
    const int n = w * 2 + hi;
    float fr[96];
    {
        const float4* fp = (const float4*)(fw + f * 96);
#pragma unroll
        for (int c = 0; c < 24; ++c) {
            const float4 t = fp[c];
            fr[4 * c] = t.x; fr[4 * c + 1] = t.y; fr[4 * c + 2] = t.z; fr[4 * c + 3] = t.w;
        }
    }
    float acc = fb[f];
    const float c0 = o0[n * DD + f], c1 = o1[n * DD + f], c2 = o2[n * DD + f];
#pragma unroll
    for (int d = 0; d < DD; ++d) acc = fmaf(__shfl(c0, hi * 32 + d), fr[d], acc);
#pragma unroll
    for (int d = 0; d < DD; ++d) acc = fmaf(__shfl(c1, hi * 32 + d), fr[32 + d], acc);
#pragma unroll
    for (int d = 0; d < DD; ++d) acc = fmaf(__shfl(c2, hi * 32 + d), fr[64 + d], acc);
    float s1 = acc, s2 = acc * acc;
#pragma unroll
    for (int o = 16; o >= 1; o >>= 1) {
        s1 += __shfl_xor(s1, o);
        s2 += __shfl_xor(s2, o);
    }
    const float m = s1 * (1.f / 32.f);
    const float v = s2 * (1.f / 32.f) - m * m;
    const float inv = rsqrtf(v + 1e-5f);
    out[n * DD + f] = fmaxf(fmaf((acc - m) * inv, g[f], b[f]), 0.f);
}

// ================= fallback kernels (ws too small) =================
__global__ __launch_bounds__(256) void prep_stats_par(const float* __restrict__ w,
                                                      const float* __restrict__ b,
                                                      float* __restrict__ st) {
    const int t = threadIdx.x;
    const int r0 = blockIdx.x * 16;
    const int k = t >> 4, j = t & 15;
    float acc = 0.f;
#pragma unroll
    for (int r = 0; r < 16; ++r)
        acc = fmaf(w[(r0 + r) * DEDGE + k], w[(r0 + r) * DEDGE + j], acc);
    atomicAdd(&st[t], acc * (1.f / D2V));
    if (t < DEDGE) {
        float s = 0.f, q = 0.f;
#pragma unroll
        for (int r = 0; r < 16; ++r) {
            s += w[(r0 + r) * DEDGE + t];
            q = fmaf(b[r0 + r], w[(r0 + r) * DEDGE + t], q);
        }
        atomicAdd(&st[256 + t], s * (1.f / D2V));
        atomicAdd(&st[272 + t], q * (1.f / D2V));
    } else if (t == 16) {
        float s = 0.f, s2 = 0.f;
#pragma unroll
        for (int r = 0; r < 16; ++r) {
            s += b[r0 + r];
            s2 = fmaf(b[r0 + r], b[r0 + r], s2);
        }
        atomicAdd(&st[288], s * (1.f / D2V));
        atomicAdd(&st[289], s2 * (1.f / D2V));
    }
}

__global__ __launch_bounds__(256) void edge_kernel_fb(
    const float* __restrict__ x, const int* __restrict__ ei,
    const float* __restrict__ eattr,
    const float* __restrict__ w, const float* __restrict__ wb,
    const float* __restrict__ lg, const float* __restrict__ lb,
    const float* __restrict__ st, float* __restrict__ out) {
    const int wv = threadIdx.x >> 6;
    const int lane = threadIdx.x & 63;
    const int W = blockIdx.x * 4 + wv;
    const int e = (W >> 2) * 64 + lane;
    const int f0 = (W & 3) * 8;
    const int si = ei[e];
    const int ti = ei[EE + e];
    float ea[16];
    {
        const float4* ep = (const float4*)(eattr + e * DEDGE);
#pragma unroll
        for (int c = 0; c < 4; ++c) {
            const float4 t = ep[c];
            ea[4 * c] = t.x; ea[4 * c + 1] = t.y; ea[4 * c + 2] = t.z; ea[4 * c + 3] = t.w;
        }
    }
    float m = st[288];
#pragma unroll
    for (int k = 0; k < 16; ++k) m = fmaf(st[256 + k], ea[k], m);
    float ex2 = st[289];
#pragma unroll
    for (int k = 0; k < 16; ++k) {
        float t = 2.f * st[272 + k];
#pragma unroll
        for (int j = 0; j < 16; ++j) t = fmaf(st[k * 16 + j], ea[j], t);
        ex2 = fmaf(t, ea[k], ex2);
    }
    const float var = fmaxf(ex2 - m * m, 0.f);
    const float inv = rsqrtf(var + 1e-5f);
    const float nm = -m;
    const float* xp = x + si * DD;
    float msg[8] = {0.f, 0.f, 0.f, 0.f, 0.f, 0.f, 0.f, 0.f};
#pragma unroll 1
    for (int d = 0; d < DD; ++d) {
        const float xd = xp[d];
        const int r0 = d * 32 + f0;
        const float* wr = w + r0 * DEDGE;
        const float* br = wb + r0;
        const float* gr = lg + r0;
        const float* b2r = lb + r0;
#pragma unroll
        for (int f = 0; f < 8; ++f) {
            float h = br[f];
#pragma unroll
            for (int k = 0; k < 16; ++k) h = fmaf(wr[f * 16 + k], ea[k], h);
            const float t1 = inv * gr[f];
            const float t2 = fmaf(nm, t1, b2r[f]);
            float val = fmaf(h, t1, t2);
            val = fmaxf(val, 0.f);
            msg[f] = fmaf(xd, val, msg[f]);
        }
    }
#pragma unroll
    for (int f = 0; f < 8; ++f) atomicAdd(&out[ti * DD + f0 + f], msg[f]);
}

__global__ __launch_bounds__(256) void node_kernel_fb(
    const float* __restrict__ x, const float* __restrict__ agg,
    const float* __restrict__ root_w, const float* __restrict__ conv_b,
    const float* __restrict__ res_w, const float* __restrict__ res_b,
    const float* __restrict__ lng, const float* __restrict__ lnb,
    float* __restrict__ out) {
    __shared__ float wsm[D2V];
    __shared__ float bs[DD], gs[DD], bbs[DD];
    for (int i = threadIdx.x; i < D2V; i += 256) wsm[i] = root_w[i] + res_w[i];
    if (threadIdx.x < DD) {
        bs[threadIdx.x] = conv_b[threadIdx.x] + res_b[threadIdx.x];
        gs[threadIdx.x] = lng[threadIdx.x];
        bbs[threadIdx.x] = lnb[threadIdx.x];
    }
    __syncthreads();
    const int n = blockIdx.x * 256 + threadIdx.x;
    if (n >= NN) return;
    float xr[DD], pre[DD];
    {
        const float4* p = (const float4*)(x + n * DD);
        const float4* q = (const float4*)(agg + n * DD);
#pragma unroll
        for (int c = 0; c < 8; ++c) {
            const float4 t = p[c];
            xr[4 * c] = t.x; xr[4 * c + 1] = t.y; xr[4 * c + 2] = t.z; xr[4 * c + 3] = t.w;
            const float4 u = q[c];
            pre[4 * c] = u.x; pre[4 * c + 1] = u.y; pre[4 * c + 2] = u.z; pre[4 * c + 3] = u.w;
        }
    }
    float s1 = 0.f, s2 = 0.f;
#pragma unroll
    for (int ff = 0; ff < DD; ++ff) {
        float acc = pre[ff] + bs[ff];
        const float* wr = wsm + ff * DD;
#pragma unroll
        for (int dd = 0; dd < DD; ++dd) acc = fmaf(xr[dd], wr[dd], acc);
        pre[ff] = acc;
        s1 += acc;
        s2 = fmaf(acc, acc, s2);
    }
    const float m = s1 * (1.f / 32.f);
    const float v = s2 * (1.f / 32.f) - m * m;
    const float inv = rsqrtf(v + 1e-5f);
    float4* op = (float4*)(out + n * DD);
#pragma unroll
    for (int c = 0; c < 8; ++c) {
        float4 t;
        t.x = fmaf((pre[4 * c + 0] - m) * inv, gs[4 * c + 0], bbs[4 * c + 0]);
        t.y = fmaf((pre[4 * c + 1] - m) * inv, gs[4 * c + 1], bbs[4 * c + 1]);
        t.z = fmaf((pre[4 * c + 2] - m) * inv, gs[4 * c + 2], bbs[4 * c + 2]);
        t.w = fmaf((pre[4 * c + 3] - m) * inv, gs[4 * c + 3], bbs[4 * c + 3]);
        op[c] = t;
    }
}

extern "C" void kernel_launch(void* const* d_in, const int* in_sizes, int n_in,
                              void* d_out, int out_size, void* d_ws, size_t ws_size,
                              hipStream_t stream) {
    const float* x   = (const float*)d_in[0];
    const int*   ei  = (const int*)d_in[1];
    const float* ea  = (const float*)d_in[2];
    const float* emw = (const float*)d_in[3];
    const float* emb = (const float*)d_in[4];
    const float* elg = (const float*)d_in[5];
    const float* elb = (const float*)d_in[6];
    const float* rootw = (const float*)d_in[7];
    const float* convb = (const float*)d_in[8];
    const float* resw  = (const float*)d_in[9];
    const float* resb  = (const float*)d_in[10];
    const float* lng   = (const float*)d_in[11];
    const float* lnb   = (const float*)d_in[12];
    const float* fw    = (const float*)d_in[13];
    const float* fb    = (const float*)d_in[14];
    const float* flg   = (const float*)d_in[15];
    const float* flb   = (const float*)d_in[16];

    // primary layout: uint4 frags | msg | out0 | out1 | st | cur | off | perm | sperm
    const size_t U4N = 2048 * 3 + (size_t)NTILE * 64 * 3;  // 486144 uint4
    const size_t FR0 = U4N * 4;                            // float index of msg
    const size_t FTOT = FR0 + (size_t)EE * DD + 2 * (size_t)NN * DD + 320;
    const size_t ITOT = 2 * (NN + 1) + 2 * (size_t)EE;
    const size_t PRIMARY_NEED = FTOT * 4 + ITOT * 4 + 256;

    if (ws_size >= PRIMARY_NEED) {
        uint4* u4 = (uint4*)d_ws;
        uint4* afh = u4;
        uint4* afl = afh + 2048;
        uint4* a2f = afl + 2048;
        uint4* bfh = a2f + 2048;
        uint4* bfl = bfh + (size_t)NTILE * 64;
        uint4* b2f = bfl + (size_t)NTILE * 64;
        float* wsf = (float*)d_ws;
        float* msg  = wsf + FR0;
        float* out0 = msg + (size_t)EE * DD;
        float* out1 = out0 + NN * DD;
        float* st   = out1 + NN * DD;
        int* cur   = (int*)(st + 320);
        int* off   = cur + (NN + 1);
        int* perm  = off + (NN + 1);
        int* sperm = perm + EE;

        hipMemsetAsync(st, 0, (320 + NN + 1) * sizeof(float), stream);
        setup1_kernel<<<385, 256, 0, stream>>>(ei, emw, emb, elg, elb, cur, st, afh, afl, a2f);
        scan_kernel<<<1, 1024, 0, stream>>>(cur, off);
        scatter_kernel<<<313, 256, 0, stream>>>(ei, cur, perm);
        stats_edge_perm<<<313, 256, 0, stream>>>(ea, st, perm, ei, bfh, bfl, b2f, sperm);

        // layer 0
        edge_mfma_kernel<<<625, 256, 0, stream>>>(x, sperm, afh, afl, a2f, bfh, bfl, b2f, msg);
        node_wave_kernel<<<1250, 256, 0, stream>>>(x, msg, off,
            rootw, convb, resw, resb, lng, lnb, out0);
        // layer 1
        edge_mfma_kernel<<<625, 256, 0, stream>>>(out0, sperm, afh, afl, a2f, bfh, bfl, b2f, msg);
        node_wave_kernel<<<1250, 256, 0, stream>>>(out0, msg, off,
            rootw + D2V, convb + DD, resw + D2V, resb + DD, lng + DD, lnb + DD, out1);
        // layer 2 + fusion head
        edge_mfma_kernel<<<625, 256, 0, stream>>>(out1, sperm, afh, afl, a2f, bfh, bfl, b2f, msg);
        node_fuse_kernel<<<1250, 256, 0, stream>>>(out1, msg, off,
            rootw + 2 * D2V, convb + 2 * DD, resw + 2 * D2V, resb + 2 * DD,
            lng + 2 * DD, lnb + 2 * DD,
            out0, out1, fw, fb, flg, flb, (float*)d_out);
    } else {
        float* wsf = (float*)d_ws;
        float* agg  = wsf;
        float* out0 = wsf + NN * DD;
        float* out1 = out0 + NN * DD;
        float* out2 = out1 + NN * DD;
        float* st   = wsf + 4 * NN * DD;
        float* outs[3] = {out0, out1, out2};

        hipMemsetAsync(st, 0, 320 * sizeof(float), stream);
        prep_stats_par<<<64, 256, 0, stream>>>(emw, emb, st);
        const float* xin = x;
        for (int l = 0; l < LL; ++l) {
            hipMemsetAsync(agg, 0, NN * DD * sizeof(float), stream);
            edge_kernel_fb<<<1250, 256, 0, stream>>>(xin, ei, ea, emw, emb, elg, elb, st, agg);
            node_kernel_fb<<<40, 256, 0, stream>>>(xin, agg,
                rootw + l * D2V, convb + l * DD, resw + l * D2V, resb + l * DD,
                lng + l * DD, lnb + l * DD, outs[l]);
            xin = outs[l];
        }
        fuse_wave_kernel<<<1250, 256, 0, stream>>>(out0, out1, out2, fw, fb, flg, flb,
                                                   (float*)d_out);
    }
}